// Round 1
// baseline (2634.897 us; speedup 1.0000x reference)
//
#include <hip/hip_runtime.h>
#include <math.h>

#define D_MODEL 1024
#define NUM_HEADS 16
#define D_HEAD 64
#define SEQ 2048
#define BATCH 2
#define NROWS (BATCH * SEQ) /* 4096 */

// ---------------------------------------------------------------------------
// GEMM: out = X @ W^T + bias.  X:[N,1024] row-major, W:[1024,1024] row-major
// (out_dim-major, so X@W^T is a dot of two contiguous rows -> NT GEMM).
// qkv_mode=1: scatter into [B,H,S,Dh] layout.  qkv_mode=0: row-major [N,D].
// blockIdx.z selects which (W,bias,out) triple (Q/K/V fused in one launch).
// 64x64 tile, TK=32, 4x4 microtile per thread, 256 threads.
// ---------------------------------------------------------------------------
__global__ __launch_bounds__(256) void gemm_nt(
    const float* __restrict__ X,
    const float* __restrict__ W0, const float* __restrict__ B0, float* __restrict__ O0,
    const float* __restrict__ W1, const float* __restrict__ B1, float* __restrict__ O1,
    const float* __restrict__ W2, const float* __restrict__ B2, float* __restrict__ O2,
    int qkv_mode)
{
    const int sel = blockIdx.z;
    const float* W    = sel == 0 ? W0 : sel == 1 ? W1 : W2;
    const float* bias = sel == 0 ? B0 : sel == 1 ? B1 : B2;
    float* out        = sel == 0 ? O0 : sel == 1 ? O1 : O2;

    __shared__ float As[64][33];   // +1 pad: row-indexed column reads hit distinct banks
    __shared__ float Bs[64][33];

    const int t  = threadIdx.x;
    const int n0 = blockIdx.y * 64;
    const int o0 = blockIdx.x * 64;

    const int lr = t >> 3;         // 0..31 load row
    const int lc = (t & 7) * 4;    // 0..28 load col (float4)

    const int tm = (t >> 4) * 4;   // 0..60 out row within tile
    const int tn = (t & 15) * 4;   // 0..60 out col within tile

    float acc[4][4] = {};

    for (int k0 = 0; k0 < D_MODEL; k0 += 32) {
#pragma unroll
        for (int rr = 0; rr < 2; ++rr) {
            const int row = lr + rr * 32;
            float4 va = *(const float4*)&X[(size_t)(n0 + row) * D_MODEL + k0 + lc];
            As[row][lc + 0] = va.x; As[row][lc + 1] = va.y;
            As[row][lc + 2] = va.z; As[row][lc + 3] = va.w;
            float4 vb = *(const float4*)&W[(size_t)(o0 + row) * D_MODEL + k0 + lc];
            Bs[row][lc + 0] = vb.x; Bs[row][lc + 1] = vb.y;
            Bs[row][lc + 2] = vb.z; Bs[row][lc + 3] = vb.w;
        }
        __syncthreads();
#pragma unroll
        for (int ks = 0; ks < 32; ++ks) {
            float a[4], b[4];
#pragma unroll
            for (int i = 0; i < 4; ++i) a[i] = As[tm + i][ks];
#pragma unroll
            for (int j = 0; j < 4; ++j) b[j] = Bs[tn + j][ks];
#pragma unroll
            for (int i = 0; i < 4; ++i)
#pragma unroll
                for (int j = 0; j < 4; ++j)
                    acc[i][j] += a[i] * b[j];
        }
        __syncthreads();
    }

    if (qkv_mode) {
        // tile spans exactly one head (o0 multiple of 64)
        const int h = o0 >> 6;
#pragma unroll
        for (int i = 0; i < 4; ++i) {
            const int n = n0 + tm + i;
            const int b = n >> 11;        // n / SEQ
            const int s = n & (SEQ - 1);
            float* dst = &out[(((size_t)(b * NUM_HEADS + h) * SEQ) + s) * D_HEAD + tn];
#pragma unroll
            for (int j = 0; j < 4; ++j) dst[j] = acc[i][j] + bias[o0 + tn + j];
        }
    } else {
#pragma unroll
        for (int i = 0; i < 4; ++i) {
            const int n = n0 + tm + i;
            float* dst = &out[(size_t)n * D_MODEL + o0 + tn];
#pragma unroll
            for (int j = 0; j < 4; ++j) dst[j] = acc[i][j] + bias[o0 + tn + j];
        }
    }
}

// ---------------------------------------------------------------------------
// Flash-style causal attention.  One block = one (b, h, 64-query tile).
// Online softmax (running m, l per query row); O accumulator in registers.
// K and V share one LDS buffer (serialized load) to stay under 64 KB/block.
// Thread t -> query row q = t>>2, 16-wide column slice c0 = (t&3)*16.
// ---------------------------------------------------------------------------
__global__ __launch_bounds__(256) void attn_fwd(
    const float* __restrict__ Q, const float* __restrict__ K,
    const float* __restrict__ V, float* __restrict__ ctx)
{
    __shared__ float Qs[64][65];
    __shared__ float KVs[64][65];   // holds K tile, then V tile
    __shared__ float Sc[64][65];
    __shared__ float mrow[64], lrow[64], arow[64];

    const int t  = threadIdx.x;
    const int qt = blockIdx.x;   // 0..31 query tile
    const int h  = blockIdx.y;
    const int b  = blockIdx.z;

    const size_t bh_off = (size_t)(b * NUM_HEADS + h) * SEQ * D_HEAD;
    const int q0 = qt * 64;

    // Load Q tile (4096 contiguous floats)
    {
        const float* src = Q + bh_off + (size_t)q0 * D_HEAD;
        for (int i = t * 4; i < 4096; i += 1024) {
            float4 v = *(const float4*)&src[i];
            const int r = i >> 6, c = i & 63;
            Qs[r][c + 0] = v.x; Qs[r][c + 1] = v.y;
            Qs[r][c + 2] = v.z; Qs[r][c + 3] = v.w;
        }
    }
    if (t < 64) { mrow[t] = -__builtin_inff(); lrow[t] = 0.f; }

    const int q  = t >> 2;        // 0..63
    const int c0 = (t & 3) * 16;  // 0..48

    float Oacc[16];
#pragma unroll
    for (int i = 0; i < 16; ++i) Oacc[i] = 0.f;

    const float scale = 0.125f;   // 1/sqrt(D_HEAD)

    for (int j = 0; j <= qt; ++j) {
        __syncthreads();  // previous iteration's LDS reads complete
        {   // K tile -> KVs
            const float* ksrc = K + bh_off + (size_t)j * 64 * D_HEAD;
            for (int i = t * 4; i < 4096; i += 1024) {
                float4 v = *(const float4*)&ksrc[i];
                const int r = i >> 6, c = i & 63;
                KVs[r][c + 0] = v.x; KVs[r][c + 1] = v.y;
                KVs[r][c + 2] = v.z; KVs[r][c + 3] = v.w;
            }
        }
        __syncthreads();

        // scores: Sc[q][c0..c0+15] = (Q[q,:] . K[k,:]) * scale  (+ causal mask)
        float sc[16];
#pragma unroll
        for (int kk = 0; kk < 16; ++kk) sc[kk] = 0.f;
#pragma unroll 4
        for (int d = 0; d < 64; ++d) {
            const float qv = Qs[q][d];
#pragma unroll
            for (int kk = 0; kk < 16; ++kk)
                sc[kk] += qv * KVs[c0 + kk][d];
        }
        const bool diag = (j == qt);
#pragma unroll
        for (int kk = 0; kk < 16; ++kk) {
            float s = sc[kk] * scale;
            if (diag && (c0 + kk) > q) s = -__builtin_inff();
            Sc[q][c0 + kk] = s;
        }
        __syncthreads();  // scores visible; K tile no longer needed

        {   // V tile -> KVs (overwrites K tile)
            const float* vsrc = V + bh_off + (size_t)j * 64 * D_HEAD;
            for (int i = t * 4; i < 4096; i += 1024) {
                float4 v = *(const float4*)&vsrc[i];
                const int r = i >> 6, c = i & 63;
                KVs[r][c + 0] = v.x; KVs[r][c + 1] = v.y;
                KVs[r][c + 2] = v.z; KVs[r][c + 3] = v.w;
            }
        }
        // online softmax row update (wave 0 only; overlaps V load issue)
        if (t < 64) {
            float mt = -__builtin_inff();
            for (int kk = 0; kk < 64; ++kk) mt = fmaxf(mt, Sc[t][kk]);
            const float mo = mrow[t];
            const float mn = fmaxf(mo, mt);
            const float al = expf(mo - mn);   // 0 when mo = -inf
            float sum = 0.f;
            for (int kk = 0; kk < 64; ++kk) {
                const float p = expf(Sc[t][kk] - mn);
                Sc[t][kk] = p;
                sum += p;
            }
            mrow[t] = mn;
            lrow[t] = al * lrow[t] + sum;
            arow[t] = al;
        }
        __syncthreads();

        // O update: O[q][c0+i] = al*O + sum_k p[q][k] * V[k][c0+i]
        const float al = arow[q];
#pragma unroll
        for (int i = 0; i < 16; ++i) Oacc[i] *= al;
        for (int kk = 0; kk < 64; ++kk) {
            const float p = Sc[q][kk];
#pragma unroll
            for (int i = 0; i < 16; ++i)
                Oacc[i] += p * KVs[kk][c0 + i];
        }
    }

    // write ctx[b, s, h*64 + c0 .. +15]  (normalized)
    const float inv = 1.f / lrow[q];
    const int n = b * SEQ + q0 + q;
    float* dst = &ctx[(size_t)n * D_MODEL + h * D_HEAD + c0];
#pragma unroll
    for (int i = 0; i < 16; i += 4) {
        float4 v = { Oacc[i] * inv, Oacc[i + 1] * inv,
                     Oacc[i + 2] * inv, Oacc[i + 3] * inv };
        *(float4*)&dst[i] = v;
    }
}

// ---------------------------------------------------------------------------
extern "C" void kernel_launch(void* const* d_in, const int* in_sizes, int n_in,
                              void* d_out, int out_size, void* d_ws, size_t ws_size,
                              hipStream_t stream)
{
    const float* x  = (const float*)d_in[0];
    const float* Wq = (const float*)d_in[1];
    const float* bq = (const float*)d_in[2];
    const float* Wk = (const float*)d_in[3];
    const float* bk = (const float*)d_in[4];
    const float* Wv = (const float*)d_in[5];
    const float* bv = (const float*)d_in[6];
    const float* Wo = (const float*)d_in[7];
    const float* bo = (const float*)d_in[8];
    float* out = (float*)d_out;

    float* ws = (float*)d_ws;
    const size_t MAT = (size_t)NROWS * D_MODEL;  // 4,194,304 floats
    float* Q   = ws;
    float* K   = ws + MAT;
    float* V   = ws + 2 * MAT;
    float* ctx = ws + 3 * MAT;   // total 64 MB of ws used

    // fused QKV projection: grid.z selects the weight set
    gemm_nt<<<dim3(D_MODEL / 64, NROWS / 64, 3), 256, 0, stream>>>(
        x, Wq, bq, Q, Wk, bk, K, Wv, bv, V, 1);

    // causal flash attention -> ctx [N, D_MODEL]
    attn_fwd<<<dim3(SEQ / 64, NUM_HEADS, BATCH), 256, 0, stream>>>(Q, K, V, ctx);

    // output projection -> d_out
    gemm_nt<<<dim3(D_MODEL / 64, NROWS / 64, 1), 256, 0, stream>>>(
        ctx, Wo, bo, out, Wo, bo, out, Wo, bo, out, 0);
}

// Round 2
// 888.124 us; speedup vs baseline: 2.9668x; 2.9668x over previous
//
#include <hip/hip_runtime.h>
#include <math.h>

#define D_MODEL 1024
#define NUM_HEADS 16
#define D_HEAD 64
#define SEQ 2048
#define BATCH 2
#define NROWS (BATCH * SEQ) /* 4096 */

typedef short s8v __attribute__((ext_vector_type(8)));   // 8 bf16 (4 VGPRs)
typedef float f4v __attribute__((ext_vector_type(4)));   // MFMA C/D

__device__ __forceinline__ short to_bf(float f) {
    union { float f; unsigned u; } x; x.f = f;
    unsigned r = x.u + 0x7fffu + ((x.u >> 16) & 1u);   // RNE
    return (short)(r >> 16);
}

// ---------------------------------------------------------------------------
// GEMM: out = X @ W^T + bias (fp32, unchanged known-good from R1).
// ---------------------------------------------------------------------------
__global__ __launch_bounds__(256) void gemm_nt(
    const float* __restrict__ X,
    const float* __restrict__ W0, const float* __restrict__ B0, float* __restrict__ O0,
    const float* __restrict__ W1, const float* __restrict__ B1, float* __restrict__ O1,
    const float* __restrict__ W2, const float* __restrict__ B2, float* __restrict__ O2,
    int qkv_mode)
{
    const int sel = blockIdx.z;
    const float* W    = sel == 0 ? W0 : sel == 1 ? W1 : W2;
    const float* bias = sel == 0 ? B0 : sel == 1 ? B1 : B2;
    float* out        = sel == 0 ? O0 : sel == 1 ? O1 : O2;

    __shared__ float As[64][33];
    __shared__ float Bs[64][33];

    const int t  = threadIdx.x;
    const int n0 = blockIdx.y * 64;
    const int o0 = blockIdx.x * 64;

    const int lr = t >> 3;
    const int lc = (t & 7) * 4;
    const int tm = (t >> 4) * 4;
    const int tn = (t & 15) * 4;

    float acc[4][4] = {};

    for (int k0 = 0; k0 < D_MODEL; k0 += 32) {
#pragma unroll
        for (int rr = 0; rr < 2; ++rr) {
            const int row = lr + rr * 32;
            float4 va = *(const float4*)&X[(size_t)(n0 + row) * D_MODEL + k0 + lc];
            As[row][lc + 0] = va.x; As[row][lc + 1] = va.y;
            As[row][lc + 2] = va.z; As[row][lc + 3] = va.w;
            float4 vb = *(const float4*)&W[(size_t)(o0 + row) * D_MODEL + k0 + lc];
            Bs[row][lc + 0] = vb.x; Bs[row][lc + 1] = vb.y;
            Bs[row][lc + 2] = vb.z; Bs[row][lc + 3] = vb.w;
        }
        __syncthreads();
#pragma unroll
        for (int ks = 0; ks < 32; ++ks) {
            float a[4], b[4];
#pragma unroll
            for (int i = 0; i < 4; ++i) a[i] = As[tm + i][ks];
#pragma unroll
            for (int j = 0; j < 4; ++j) b[j] = Bs[tn + j][ks];
#pragma unroll
            for (int i = 0; i < 4; ++i)
#pragma unroll
                for (int j = 0; j < 4; ++j)
                    acc[i][j] += a[i] * b[j];
        }
        __syncthreads();
    }

    if (qkv_mode) {
        const int h = o0 >> 6;
#pragma unroll
        for (int i = 0; i < 4; ++i) {
            const int n = n0 + tm + i;
            const int b = n >> 11;
            const int s = n & (SEQ - 1);
            float* dst = &out[(((size_t)(b * NUM_HEADS + h) * SEQ) + s) * D_HEAD + tn];
#pragma unroll
            for (int j = 0; j < 4; ++j) dst[j] = acc[i][j] + bias[o0 + tn + j];
        }
    } else {
#pragma unroll
        for (int i = 0; i < 4; ++i) {
            const int n = n0 + tm + i;
            float* dst = &out[(size_t)n * D_MODEL + o0 + tn];
#pragma unroll
            for (int j = 0; j < 4; ++j) dst[j] = acc[i][j] + bias[o0 + tn + j];
        }
    }
}

// ---------------------------------------------------------------------------
// MFMA flash attention. Block = (b, h, 64-query tile); 4 waves, wave w owns
// 16-query strip. mfma_f32_16x16x32_bf16; A/B frag row=lane&15, k=quad*8+j;
// C/D col=lane&15, row=quad*4+reg (m89/m120-verified layouts).
// Q frags in registers (scale folded); K staged bf16 Kb[key][d]; V staged
// TRANSPOSED Vt[d][key] so PV B-frags are ds_read_b128; online softmax in
// registers via shfl_xor over the 16-lane col groups; P round-trips through
// per-wave Ps[16][72] (C-layout -> A-layout).
// ---------------------------------------------------------------------------
#define KSTR 72   /* bf16 elems; 144 B row stride, 16B aligned, odd bank-group */

__global__ __launch_bounds__(256) void attn_mfma(
    const float* __restrict__ Q, const float* __restrict__ K,
    const float* __restrict__ V, float* __restrict__ ctx)
{
    __shared__ short Kb[64 * KSTR];        // 9216 B
    __shared__ short Vt[64 * KSTR];        // 9216 B
    __shared__ short Ps[4][16 * KSTR];     // 9216 B

    const int t    = threadIdx.x;
    const int w    = t >> 6;
    const int lane = t & 63;
    const int quad = lane >> 4;
    const int l15  = lane & 15;
    const int qt   = (int)(gridDim.x - 1) - (int)blockIdx.x;  // heavy blocks first
    const int h    = blockIdx.y;
    const int b    = blockIdx.z;
    const size_t bh = (size_t)(b * NUM_HEADS + h) * SEQ * D_HEAD;
    const int q0   = qt * 64;

    // Q fragments for this wave's 16-row strip, 1/sqrt(Dh) folded in.
    s8v aq[2];
    {
        const float* qp = Q + bh + (size_t)(q0 + w * 16 + l15) * D_HEAD + quad * 8;
#pragma unroll
        for (int c = 0; c < 2; ++c)
#pragma unroll
            for (int j2 = 0; j2 < 8; ++j2)
                aq[c][j2] = to_bf(qp[c * 32 + j2] * 0.125f);
    }

    f4v Oacc[4];
#pragma unroll
    for (int i = 0; i < 4; ++i) Oacc[i] = (f4v){0.f, 0.f, 0.f, 0.f};
    float mrun[4], lrun[4];
#pragma unroll
    for (int r = 0; r < 4; ++r) { mrun[r] = -INFINITY; lrun[r] = 0.f; }

    for (int j = 0; j <= qt; ++j) {
        __syncthreads();   // prev iter's Kb/Vt readers done
        {
            // K tile -> Kb[key][d] bf16 (coalesced float4 reads, 8B LDS writes)
            const float* kp = K + bh + (size_t)j * 64 * D_HEAD;
#pragma unroll
            for (int it = 0; it < 4; ++it) {
                int i = t * 4 + it * 1024;
                int key = i >> 6, d = i & 63;
                float4 v = *(const float4*)&kp[i];
                short4 s;
                s.x = to_bf(v.x); s.y = to_bf(v.y);
                s.z = to_bf(v.z); s.w = to_bf(v.w);
                *(short4*)&Kb[key * KSTR + d] = s;
            }
            // V tile -> Vt[d][key] bf16 (thread does keys {2a,2a+1} x 8 d's,
            // packs both keys into one dword write)
            const float* vp = V + bh + (size_t)j * 64 * D_HEAD;
            const int a = t >> 3, dbase = (t & 7) * 8;
            float4 p0 = *(const float4*)&vp[(2 * a) * 64 + dbase];
            float4 p1 = *(const float4*)&vp[(2 * a) * 64 + dbase + 4];
            float4 p2 = *(const float4*)&vp[(2 * a + 1) * 64 + dbase];
            float4 p3 = *(const float4*)&vp[(2 * a + 1) * 64 + dbase + 4];
            float r0[8] = {p0.x, p0.y, p0.z, p0.w, p1.x, p1.y, p1.z, p1.w};
            float r1[8] = {p2.x, p2.y, p2.z, p2.w, p3.x, p3.y, p3.z, p3.w};
#pragma unroll
            for (int i = 0; i < 8; ++i) {
                unsigned lo = (unsigned short)to_bf(r0[i]);
                unsigned hi = (unsigned short)to_bf(r1[i]);
                *(unsigned*)&Vt[(dbase + i) * KSTR + 2 * a] = lo | (hi << 16);
            }
        }
        __syncthreads();

        // S = Qhat @ K^T : 4 n-tiles x 2 k-chunks
        f4v S[4];
#pragma unroll
        for (int nt = 0; nt < 4; ++nt) {
            S[nt] = (f4v){0.f, 0.f, 0.f, 0.f};
#pragma unroll
            for (int c = 0; c < 2; ++c) {
                s8v bk = *(const s8v*)&Kb[(nt * 16 + l15) * KSTR + c * 32 + quad * 8];
                S[nt] = __builtin_amdgcn_mfma_f32_16x16x32_bf16(aq[c], bk, S[nt], 0, 0, 0);
            }
        }

        // causal mask (diagonal tile only; j*64 == q0 there)
        if (j == qt) {
#pragma unroll
            for (int nt = 0; nt < 4; ++nt)
#pragma unroll
                for (int r = 0; r < 4; ++r)
                    if (nt * 16 + l15 > w * 16 + quad * 4 + r) S[nt][r] = -INFINITY;
        }

        // online softmax, all in registers
        float mt[4];
#pragma unroll
        for (int r = 0; r < 4; ++r)
            mt[r] = fmaxf(fmaxf(S[0][r], S[1][r]), fmaxf(S[2][r], S[3][r]));
#pragma unroll
        for (int mk = 1; mk < 16; mk <<= 1)
#pragma unroll
            for (int r = 0; r < 4; ++r)
                mt[r] = fmaxf(mt[r], __shfl_xor(mt[r], mk, 64));

        float al[4], rs[4];
#pragma unroll
        for (int r = 0; r < 4; ++r) {
            float mn = fmaxf(mrun[r], mt[r]);
            al[r] = exp2f((mrun[r] - mn) * 1.44269504f);   // 0 when mrun=-inf
            mrun[r] = mn;
            rs[r] = 0.f;
        }
#pragma unroll
        for (int nt = 0; nt < 4; ++nt)
#pragma unroll
            for (int r = 0; r < 4; ++r) {
                float p = exp2f((S[nt][r] - mrun[r]) * 1.44269504f);  // masked -> 0
                rs[r] += p;
                Ps[w][(quad * 4 + r) * KSTR + nt * 16 + l15] = to_bf(p);
            }
#pragma unroll
        for (int mk = 1; mk < 16; mk <<= 1)
#pragma unroll
            for (int r = 0; r < 4; ++r)
                rs[r] += __shfl_xor(rs[r], mk, 64);
#pragma unroll
        for (int r = 0; r < 4; ++r) {
            lrun[r] = al[r] * lrun[r] + rs[r];
#pragma unroll
            for (int nt = 0; nt < 4; ++nt) Oacc[nt][r] *= al[r];
        }

        // O += P @ V  (Ps is wave-private: no barrier, lgkmcnt handles RAW)
#pragma unroll
        for (int c = 0; c < 2; ++c) {
            s8v ap = *(const s8v*)&Ps[w][l15 * KSTR + c * 32 + quad * 8];
#pragma unroll
            for (int nt = 0; nt < 4; ++nt) {
                s8v bv = *(const s8v*)&Vt[(nt * 16 + l15) * KSTR + c * 32 + quad * 8];
                Oacc[nt] = __builtin_amdgcn_mfma_f32_16x16x32_bf16(ap, bv, Oacc[nt], 0, 0, 0);
            }
        }
    }

    // normalize + write ctx[b, s, h*64 + dh]
#pragma unroll
    for (int r = 0; r < 4; ++r) {
        float inv = 1.f / lrun[r];
        int n = b * SEQ + q0 + w * 16 + quad * 4 + r;
        float* dst = &ctx[(size_t)n * D_MODEL + h * D_HEAD + l15];
#pragma unroll
        for (int nt = 0; nt < 4; ++nt)
            dst[nt * 16] = Oacc[nt][r] * inv;
    }
}

// ---------------------------------------------------------------------------
extern "C" void kernel_launch(void* const* d_in, const int* in_sizes, int n_in,
                              void* d_out, int out_size, void* d_ws, size_t ws_size,
                              hipStream_t stream)
{
    const float* x  = (const float*)d_in[0];
    const float* Wq = (const float*)d_in[1];
    const float* bq = (const float*)d_in[2];
    const float* Wk = (const float*)d_in[3];
    const float* bk = (const float*)d_in[4];
    const float* Wv = (const float*)d_in[5];
    const float* bv = (const float*)d_in[6];
    const float* Wo = (const float*)d_in[7];
    const float* bo = (const float*)d_in[8];
    float* out = (float*)d_out;

    float* ws = (float*)d_ws;
    const size_t MAT = (size_t)NROWS * D_MODEL;
    float* Q   = ws;
    float* K   = ws + MAT;
    float* V   = ws + 2 * MAT;
    float* ctx = ws + 3 * MAT;

    gemm_nt<<<dim3(D_MODEL / 64, NROWS / 64, 3), 256, 0, stream>>>(
        x, Wq, bq, Q, Wk, bk, K, Wv, bv, V, 1);

    attn_mfma<<<dim3(SEQ / 64, NUM_HEADS, BATCH), 256, 0, stream>>>(Q, K, V, ctx);

    gemm_nt<<<dim3(D_MODEL / 64, NROWS / 64, 1), 256, 0, stream>>>(
        ctx, Wo, bo, out, Wo, bo, out, Wo, bo, out, 0);
}

// Round 3
// 314.920 us; speedup vs baseline: 8.3669x; 2.8202x over previous
//
#include <hip/hip_runtime.h>
#include <math.h>

#define D_MODEL 1024
#define NUM_HEADS 16
#define D_HEAD 64
#define SEQ 2048
#define BATCH 2
#define NROWS (BATCH * SEQ) /* 4096 */

typedef short s8v __attribute__((ext_vector_type(8)));   // 8 bf16 (4 VGPRs)
typedef float f4v __attribute__((ext_vector_type(4)));   // MFMA C/D

__device__ __forceinline__ short to_bf(float f) {
    union { float f; unsigned u; } x; x.f = f;
    unsigned r = x.u + 0x7fffu + ((x.u >> 16) & 1u);   // RNE
    return (short)(r >> 16);
}

// async global->LDS, 16 B per lane; LDS dest is wave-uniform base + lane*16
__device__ __forceinline__ void gld_lds16(const short* g, short* l) {
    __builtin_amdgcn_global_load_lds(
        (const __attribute__((address_space(1))) unsigned*)g,
        (__attribute__((address_space(3))) unsigned*)l, 16, 0, 0);
}

// ---------------------------------------------------------------------------
// fp32 -> bf16 convert: x -> Xb, {Wq,Wk,Wv} -> Wqkvb (fused [3072,1024]), Wo -> Wob
// ---------------------------------------------------------------------------
__global__ __launch_bounds__(256) void cvt_fused(
    const float* __restrict__ x,  const float* __restrict__ Wq,
    const float* __restrict__ Wk, const float* __restrict__ Wv,
    const float* __restrict__ Wo,
    short* __restrict__ Xb, short* __restrict__ Wqkvb, short* __restrict__ Wob)
{
    const int NX = NROWS * D_MODEL / 4;     // float4 count: 1,048,576
    const int NW = D_MODEL * D_MODEL / 4;   //               262,144
    int j = blockIdx.x * 256 + threadIdx.x;
    const float* src; short* dst;
    if (j < NX)                 { src = x;  dst = Xb; }
    else if ((j -= NX) < NW)    { src = Wq; dst = Wqkvb; }
    else if ((j -= NW) < NW)    { src = Wk; dst = Wqkvb + NW * 4; }
    else if ((j -= NW) < NW)    { src = Wv; dst = Wqkvb + NW * 8; }
    else                        { j -= NW; src = Wo; dst = Wob; }
    float4 v = ((const float4*)src)[j];
    short4 s = { to_bf(v.x), to_bf(v.y), to_bf(v.z), to_bf(v.w) };
    ((short4*)dst)[j] = s;
}

// ---------------------------------------------------------------------------
// bf16 MFMA GEMM (m97 structure): out = X @ W^T + bias.
// X:[M,1024] bf16 row-major, W:[N,1024] bf16 row-major (NT).
// 128x128 tile, BK=64, 256 thr = 4 waves (2x2), 64x64 per wave.
// global_load_lds width=16 staging; 32 MFMA + 16 ds_read_b128 per K-step.
// qkv_mode=1: N=3072 fused; epilogue scatters into Q/K/V [B,H,S,Dh] fp32.
// qkv_mode=0: row-major [M, N] fp32 out.
// ---------------------------------------------------------------------------
__global__ __launch_bounds__(256) void gemm_bf16(
    const short* __restrict__ Xb, const short* __restrict__ Wb,
    const float* __restrict__ B0, const float* __restrict__ B1, const float* __restrict__ B2,
    float* __restrict__ O0, float* __restrict__ O1, float* __restrict__ O2,
    int qkv_mode)
{
    __shared__ __align__(16) short As[128 * 64];   // 16 KB
    __shared__ __align__(16) short Bs[128 * 64];   // 16 KB

    const int t    = threadIdx.x;
    const int w    = t >> 6;
    const int lane = t & 63;
    const int quad = lane >> 4;
    const int l15  = lane & 15;
    const int wm   = w & 1, wn = w >> 1;

    const int n0 = blockIdx.x * 128;
    const int m0 = blockIdx.y * 128;

    f4v acc[4][4];
#pragma unroll
    for (int i = 0; i < 4; ++i)
#pragma unroll
        for (int j = 0; j < 4; ++j) acc[i][j] = (f4v){0.f, 0.f, 0.f, 0.f};

    for (int k0 = 0; k0 < D_MODEL; k0 += 64) {
        // stage A,B tiles: 1024 16B-chunks each; chunk cid -> row=cid>>3, kc=cid&7
#pragma unroll
        for (int i = 0; i < 4; ++i) {
            const int cid = i * 256 + t;
            const int row = cid >> 3, kc = cid & 7;
            gld_lds16(&Xb[(size_t)(m0 + row) * D_MODEL + k0 + kc * 8],
                      &As[(i * 256 + w * 64) * 8]);
            gld_lds16(&Wb[(size_t)(n0 + row) * D_MODEL + k0 + kc * 8],
                      &Bs[(i * 256 + w * 64) * 8]);
        }
        __syncthreads();   // compiler emits vmcnt(0) drain before s_barrier

#pragma unroll
        for (int c = 0; c < 2; ++c) {
            s8v af[4], bf[4];
#pragma unroll
            for (int mi = 0; mi < 4; ++mi)
                af[mi] = *(const s8v*)&As[(wm * 64 + mi * 16 + l15) * 64 + c * 32 + quad * 8];
#pragma unroll
            for (int ni = 0; ni < 4; ++ni)
                bf[ni] = *(const s8v*)&Bs[(wn * 64 + ni * 16 + l15) * 64 + c * 32 + quad * 8];
#pragma unroll
            for (int mi = 0; mi < 4; ++mi)
#pragma unroll
                for (int ni = 0; ni < 4; ++ni)
                    acc[mi][ni] = __builtin_amdgcn_mfma_f32_16x16x32_bf16(
                        af[mi], bf[ni], acc[mi][ni], 0, 0, 0);
        }
        __syncthreads();   // WAR: readers done before next staging
    }

    if (qkv_mode) {
        const int sel = n0 >> 10;                       // block-uniform (128 | 1024)
        const float* bias = sel == 0 ? B0 : sel == 1 ? B1 : B2;
        float* out        = sel == 0 ? O0 : sel == 1 ? O1 : O2;
#pragma unroll
        for (int ni = 0; ni < 4; ++ni) {
            const int col = n0 + wn * 64 + ni * 16 + l15;
            const int rem = col & 1023;
            const int hh = rem >> 6, dh = rem & 63;
            const float bv = bias[rem];
#pragma unroll
            for (int mi = 0; mi < 4; ++mi)
#pragma unroll
                for (int r = 0; r < 4; ++r) {
                    const int row = m0 + wm * 64 + mi * 16 + quad * 4 + r;
                    const int bb = row >> 11, s = row & (SEQ - 1);
                    out[(((size_t)(bb * NUM_HEADS + hh) * SEQ) + s) * D_HEAD + dh]
                        = acc[mi][ni][r] + bv;
                }
        }
    } else {
#pragma unroll
        for (int ni = 0; ni < 4; ++ni) {
            const int col = n0 + wn * 64 + ni * 16 + l15;
            const float bv = B0[col];
#pragma unroll
            for (int mi = 0; mi < 4; ++mi)
#pragma unroll
                for (int r = 0; r < 4; ++r) {
                    const int row = m0 + wm * 64 + mi * 16 + quad * 4 + r;
                    O0[(size_t)row * D_MODEL + col] = acc[mi][ni][r] + bv;
                }
        }
    }
}

// ---------------------------------------------------------------------------
// MFMA flash attention (unchanged from R2 except ctx written as bf16).
// ---------------------------------------------------------------------------
#define KSTR 72

__global__ __launch_bounds__(256) void attn_mfma(
    const float* __restrict__ Q, const float* __restrict__ K,
    const float* __restrict__ V, short* __restrict__ ctxb)
{
    __shared__ short Kb[64 * KSTR];
    __shared__ short Vt[64 * KSTR];
    __shared__ short Ps[4][16 * KSTR];

    const int t    = threadIdx.x;
    const int w    = t >> 6;
    const int lane = t & 63;
    const int quad = lane >> 4;
    const int l15  = lane & 15;
    const int qt   = (int)(gridDim.x - 1) - (int)blockIdx.x;  // heavy blocks first
    const int h    = blockIdx.y;
    const int b    = blockIdx.z;
    const size_t bh = (size_t)(b * NUM_HEADS + h) * SEQ * D_HEAD;
    const int q0   = qt * 64;

    s8v aq[2];
    {
        const float* qp = Q + bh + (size_t)(q0 + w * 16 + l15) * D_HEAD + quad * 8;
#pragma unroll
        for (int c = 0; c < 2; ++c)
#pragma unroll
            for (int j2 = 0; j2 < 8; ++j2)
                aq[c][j2] = to_bf(qp[c * 32 + j2] * 0.125f);
    }

    f4v Oacc[4];
#pragma unroll
    for (int i = 0; i < 4; ++i) Oacc[i] = (f4v){0.f, 0.f, 0.f, 0.f};
    float mrun[4], lrun[4];
#pragma unroll
    for (int r = 0; r < 4; ++r) { mrun[r] = -INFINITY; lrun[r] = 0.f; }

    for (int j = 0; j <= qt; ++j) {
        __syncthreads();
        {
            const float* kp = K + bh + (size_t)j * 64 * D_HEAD;
#pragma unroll
            for (int it = 0; it < 4; ++it) {
                int i = t * 4 + it * 1024;
                int key = i >> 6, d = i & 63;
                float4 v = *(const float4*)&kp[i];
                short4 s;
                s.x = to_bf(v.x); s.y = to_bf(v.y);
                s.z = to_bf(v.z); s.w = to_bf(v.w);
                *(short4*)&Kb[key * KSTR + d] = s;
            }
            const float* vp = V + bh + (size_t)j * 64 * D_HEAD;
            const int a = t >> 3, dbase = (t & 7) * 8;
            float4 p0 = *(const float4*)&vp[(2 * a) * 64 + dbase];
            float4 p1 = *(const float4*)&vp[(2 * a) * 64 + dbase + 4];
            float4 p2 = *(const float4*)&vp[(2 * a + 1) * 64 + dbase];
            float4 p3 = *(const float4*)&vp[(2 * a + 1) * 64 + dbase + 4];
            float r0[8] = {p0.x, p0.y, p0.z, p0.w, p1.x, p1.y, p1.z, p1.w};
            float r1[8] = {p2.x, p2.y, p2.z, p2.w, p3.x, p3.y, p3.z, p3.w};
#pragma unroll
            for (int i = 0; i < 8; ++i) {
                unsigned lo = (unsigned short)to_bf(r0[i]);
                unsigned hi = (unsigned short)to_bf(r1[i]);
                *(unsigned*)&Vt[(dbase + i) * KSTR + 2 * a] = lo | (hi << 16);
            }
        }
        __syncthreads();

        f4v S[4];
#pragma unroll
        for (int nt = 0; nt < 4; ++nt) {
            S[nt] = (f4v){0.f, 0.f, 0.f, 0.f};
#pragma unroll
            for (int c = 0; c < 2; ++c) {
                s8v bk = *(const s8v*)&Kb[(nt * 16 + l15) * KSTR + c * 32 + quad * 8];
                S[nt] = __builtin_amdgcn_mfma_f32_16x16x32_bf16(aq[c], bk, S[nt], 0, 0, 0);
            }
        }

        if (j == qt) {
#pragma unroll
            for (int nt = 0; nt < 4; ++nt)
#pragma unroll
                for (int r = 0; r < 4; ++r)
                    if (nt * 16 + l15 > w * 16 + quad * 4 + r) S[nt][r] = -INFINITY;
        }

        float mt[4];
#pragma unroll
        for (int r = 0; r < 4; ++r)
            mt[r] = fmaxf(fmaxf(S[0][r], S[1][r]), fmaxf(S[2][r], S[3][r]));
#pragma unroll
        for (int mk = 1; mk < 16; mk <<= 1)
#pragma unroll
            for (int r = 0; r < 4; ++r)
                mt[r] = fmaxf(mt[r], __shfl_xor(mt[r], mk, 64));

        float al[4], rs[4];
#pragma unroll
        for (int r = 0; r < 4; ++r) {
            float mn = fmaxf(mrun[r], mt[r]);
            al[r] = exp2f((mrun[r] - mn) * 1.44269504f);
            mrun[r] = mn;
            rs[r] = 0.f;
        }
#pragma unroll
        for (int nt = 0; nt < 4; ++nt)
#pragma unroll
            for (int r = 0; r < 4; ++r) {
                float p = exp2f((S[nt][r] - mrun[r]) * 1.44269504f);
                rs[r] += p;
                Ps[w][(quad * 4 + r) * KSTR + nt * 16 + l15] = to_bf(p);
            }
#pragma unroll
        for (int mk = 1; mk < 16; mk <<= 1)
#pragma unroll
            for (int r = 0; r < 4; ++r)
                rs[r] += __shfl_xor(rs[r], mk, 64);
#pragma unroll
        for (int r = 0; r < 4; ++r) {
            lrun[r] = al[r] * lrun[r] + rs[r];
#pragma unroll
            for (int nt = 0; nt < 4; ++nt) Oacc[nt][r] *= al[r];
        }

#pragma unroll
        for (int c = 0; c < 2; ++c) {
            s8v ap = *(const s8v*)&Ps[w][l15 * KSTR + c * 32 + quad * 8];
#pragma unroll
            for (int nt = 0; nt < 4; ++nt) {
                s8v bv = *(const s8v*)&Vt[(nt * 16 + l15) * KSTR + c * 32 + quad * 8];
                Oacc[nt] = __builtin_amdgcn_mfma_f32_16x16x32_bf16(ap, bv, Oacc[nt], 0, 0, 0);
            }
        }
    }

#pragma unroll
    for (int r = 0; r < 4; ++r) {
        float inv = 1.f / lrun[r];
        int n = b * SEQ + q0 + w * 16 + quad * 4 + r;
        short* dst = &ctxb[(size_t)n * D_MODEL + h * D_HEAD + l15];
#pragma unroll
        for (int nt = 0; nt < 4; ++nt)
            dst[nt * 16] = to_bf(Oacc[nt][r] * inv);
    }
}

// ---------------------------------------------------------------------------
extern "C" void kernel_launch(void* const* d_in, const int* in_sizes, int n_in,
                              void* d_out, int out_size, void* d_ws, size_t ws_size,
                              hipStream_t stream)
{
    const float* x  = (const float*)d_in[0];
    const float* Wq = (const float*)d_in[1];
    const float* bq = (const float*)d_in[2];
    const float* Wk = (const float*)d_in[3];
    const float* bk = (const float*)d_in[4];
    const float* Wv = (const float*)d_in[5];
    const float* bv = (const float*)d_in[6];
    const float* Wo = (const float*)d_in[7];
    const float* bo = (const float*)d_in[8];
    float* out = (float*)d_out;

    float* ws = (float*)d_ws;
    const size_t MAT = (size_t)NROWS * D_MODEL;  // 4,194,304
    float* Qf   = ws;                            // fp32 [B,H,S,Dh]
    float* Kf   = ws + MAT;
    float* Vf   = ws + 2 * MAT;
    short* ctxb = (short*)(ws + 3 * MAT);        // bf16 [N, D_MODEL]
    short* Xb   = ctxb + MAT;                    // bf16 [N, D_MODEL]
    short* Wqkvb = Xb + MAT;                     // bf16 [3072, 1024]
    short* Wob   = Wqkvb + 3 * D_MODEL * D_MODEL;// bf16 [1024, 1024]

    // fp32 -> bf16 conversions (x + 4 weights): 2,097,152 float4s
    cvt_fused<<<8192, 256, 0, stream>>>(x, Wq, Wk, Wv, Wo, Xb, Wqkvb, Wob);

    // fused QKV projection (bf16 MFMA) -> Q/K/V fp32 [B,H,S,Dh]
    gemm_bf16<<<dim3(3 * D_MODEL / 128, NROWS / 128), 256, 0, stream>>>(
        Xb, Wqkvb, bq, bk, bv, Qf, Kf, Vf, 1);

    // causal flash attention -> ctx bf16 [N, D_MODEL]
    attn_mfma<<<dim3(SEQ / 64, NUM_HEADS, BATCH), 256, 0, stream>>>(Qf, Kf, Vf, ctxb);

    // output projection (bf16 MFMA) -> d_out fp32
    gemm_bf16<<<dim3(D_MODEL / 128, NROWS / 128), 256, 0, stream>>>(
        ctxb, Wob, bo, bo, bo, out, out, out, 0);
}

// Round 4
// 295.140 us; speedup vs baseline: 8.9276x; 1.0670x over previous
//
#include <hip/hip_runtime.h>
#include <math.h>

#define D_MODEL 1024
#define NUM_HEADS 16
#define D_HEAD 64
#define SEQ 2048
#define BATCH 2
#define NROWS (BATCH * SEQ) /* 4096 */

typedef short s8v __attribute__((ext_vector_type(8)));   // 8 bf16 (4 VGPRs)
typedef float f4v __attribute__((ext_vector_type(4)));   // MFMA C/D

__device__ __forceinline__ short to_bf(float f) {
    union { float f; unsigned u; } x; x.f = f;
    unsigned r = x.u + 0x7fffu + ((x.u >> 16) & 1u);   // RNE
    return (short)(r >> 16);
}

// async global->LDS, 16 B/lane; LDS dest is wave-uniform base + lane*16
__device__ __forceinline__ void gld_lds16(const short* g, short* l) {
    __builtin_amdgcn_global_load_lds(
        (const __attribute__((address_space(1))) unsigned*)g,
        (__attribute__((address_space(3))) unsigned*)l, 16, 0, 0);
}

// ---------------------------------------------------------------------------
// fp32 -> bf16 convert. Wq segment pre-scaled by 1/sqrt(Dh) = 0.125.
// ---------------------------------------------------------------------------
__global__ __launch_bounds__(256) void cvt_fused(
    const float* __restrict__ x,  const float* __restrict__ Wq,
    const float* __restrict__ Wk, const float* __restrict__ Wv,
    const float* __restrict__ Wo,
    short* __restrict__ Xb, short* __restrict__ Wqkvb, short* __restrict__ Wob)
{
    const int NX = NROWS * D_MODEL / 4;
    const int NW = D_MODEL * D_MODEL / 4;
    int j = blockIdx.x * 256 + threadIdx.x;
    const float* src; short* dst; float sc = 1.f;
    if (j < NX)                 { src = x;  dst = Xb; }
    else if ((j -= NX) < NW)    { src = Wq; dst = Wqkvb; sc = 0.125f; }
    else if ((j -= NW) < NW)    { src = Wk; dst = Wqkvb + NW * 4; }
    else if ((j -= NW) < NW)    { src = Wv; dst = Wqkvb + NW * 8; }
    else                        { j -= NW; src = Wo; dst = Wob; }
    float4 v = ((const float4*)src)[j];
    short4 s = { to_bf(v.x * sc), to_bf(v.y * sc), to_bf(v.z * sc), to_bf(v.w * sc) };
    ((short4*)dst)[j] = s;
}

// ---------------------------------------------------------------------------
// bf16 MFMA GEMM: out = X @ W^T + bias.  128x128 tile, BK=64, 4 waves.
// qkv_mode=1: writes bf16 Q [B,H,S,Dh], K [B,H,S,Dh], V^T [B,H,Dh,S],
//   repacked through LDS so global writes are contiguous 128-B runs.
//   Q bias scaled by 0.125 (Wq pre-scaled at cvt).
// qkv_mode=0: fp32 row-major [M,N] direct (d_out path).
// ---------------------------------------------------------------------------
__global__ __launch_bounds__(256) void gemm_bf16(
    const short* __restrict__ Xb, const short* __restrict__ Wb,
    const float* __restrict__ B0, const float* __restrict__ B1, const float* __restrict__ B2,
    float* __restrict__ Ofp,
    short* __restrict__ Q0, short* __restrict__ K1, short* __restrict__ V2,
    int qkv_mode)
{
    // union: staging As/Bs (16384 shorts) and epilogue tile E[128][144] (18432)
    __shared__ __align__(16) short smem[18432];
    short* As = smem;
    short* Bs = smem + 8192;

    const int t    = threadIdx.x;
    const int w    = t >> 6;
    const int lane = t & 63;
    const int quad = lane >> 4;
    const int l15  = lane & 15;
    const int wm   = w & 1, wn = w >> 1;

    const int n0 = blockIdx.x * 128;
    const int m0 = blockIdx.y * 128;

    f4v acc[4][4];
#pragma unroll
    for (int i = 0; i < 4; ++i)
#pragma unroll
        for (int j = 0; j < 4; ++j) acc[i][j] = (f4v){0.f, 0.f, 0.f, 0.f};

    for (int k0 = 0; k0 < D_MODEL; k0 += 64) {
#pragma unroll
        for (int i = 0; i < 4; ++i) {
            const int cid = i * 256 + t;
            const int row = cid >> 3, kc = cid & 7;
            gld_lds16(&Xb[(size_t)(m0 + row) * D_MODEL + k0 + kc * 8],
                      &As[(i * 256 + w * 64) * 8]);
            gld_lds16(&Wb[(size_t)(n0 + row) * D_MODEL + k0 + kc * 8],
                      &Bs[(i * 256 + w * 64) * 8]);
        }
        __syncthreads();

#pragma unroll
        for (int c = 0; c < 2; ++c) {
            s8v af[4], bf[4];
#pragma unroll
            for (int mi = 0; mi < 4; ++mi)
                af[mi] = *(const s8v*)&As[(wm * 64 + mi * 16 + l15) * 64 + c * 32 + quad * 8];
#pragma unroll
            for (int ni = 0; ni < 4; ++ni)
                bf[ni] = *(const s8v*)&Bs[(wn * 64 + ni * 16 + l15) * 64 + c * 32 + quad * 8];
#pragma unroll
            for (int mi = 0; mi < 4; ++mi)
#pragma unroll
                for (int ni = 0; ni < 4; ++ni)
                    acc[mi][ni] = __builtin_amdgcn_mfma_f32_16x16x32_bf16(
                        af[mi], bf[ni], acc[mi][ni], 0, 0, 0);
        }
        __syncthreads();
    }

    if (!qkv_mode) {
#pragma unroll
        for (int ni = 0; ni < 4; ++ni) {
            const int col = n0 + wn * 64 + ni * 16 + l15;
            const float bv = B0[col];
#pragma unroll
            for (int mi = 0; mi < 4; ++mi)
#pragma unroll
                for (int r = 0; r < 4; ++r) {
                    const int row = m0 + wm * 64 + mi * 16 + quad * 4 + r;
                    Ofp[(size_t)row * D_MODEL + col] = acc[mi][ni][r] + bv;
                }
        }
        return;
    }

    // ---- QKV epilogue: bf16 + LDS repack ----
    const int sel = n0 >> 10;                     // 0=Q 1=K 2=V (block-uniform)
    const float* bias = sel == 0 ? B0 : sel == 1 ? B1 : B2;
    short* out        = sel == 0 ? Q0 : sel == 1 ? K1 : V2;
    const float bsc   = sel == 0 ? 0.125f : 1.f;
    const int h0 = (n0 & 1023) >> 6;              // first of the 2 heads in tile

    // E[128][144] shorts; sel<2: E[row][col] ([s][dh]); sel==2: E[col][row]
#pragma unroll
    for (int ni = 0; ni < 4; ++ni) {
        const int col = wn * 64 + ni * 16 + l15;
        const float bv = bias[(n0 & 1023) + col] * bsc;
#pragma unroll
        for (int mi = 0; mi < 4; ++mi)
#pragma unroll
            for (int r = 0; r < 4; ++r) {
                const int row = wm * 64 + mi * 16 + quad * 4 + r;
                const short v = to_bf(acc[mi][ni][r] + bv);
                if (sel < 2) smem[row * 144 + col] = v;
                else         smem[col * 144 + row] = v;
            }
    }
    __syncthreads();

    // readback: thread t -> E-row rr, half of 64 shorts -> 128-B global run
    const int rr = t >> 1, half = t & 1;
    const int bb = m0 >> 11, mloc = m0 & (SEQ - 1);
    const short* src = &smem[rr * 144 + half * 64];
    short* dst;
    if (sel < 2)
        dst = out + (((size_t)(bb * NUM_HEADS + h0 + half) * SEQ + (mloc + rr)) * D_HEAD);
    else
        dst = out + ((size_t)(bb * NUM_HEADS + h0 + (rr >> 6)) * D_HEAD + (rr & 63)) * SEQ
                  + mloc + half * 64;
#pragma unroll
    for (int i = 0; i < 8; ++i)
        ((int4*)dst)[i] = ((const int4*)src)[i];
}

// ---------------------------------------------------------------------------
// MFMA flash attention, 128-query blocks, pure-DMA staging.
// Block = (b, h, 128-q tile); 4 waves, wave w owns rows w*32..w*32+31.
// K bf16 [B,H,S,Dh]; V^T bf16 [B,H,Dh,S].  LDS tiles 64x64 bf16, XOR-swizzled
// 16-B chunks: LDS(row, p) holds global chunk p^(row&7) -> b128 frag reads
// hit the 8-dword/bank minimum (conflict-free).
// ---------------------------------------------------------------------------
#define KSTR 72   /* Ps leading dim (shorts) */

__global__ __launch_bounds__(256) void attn_mfma(
    const short* __restrict__ Qg, const short* __restrict__ Kg,
    const short* __restrict__ Vg, short* __restrict__ ctxb)
{
    __shared__ __align__(16) short Kb[64 * 64];      // 8 KB
    __shared__ __align__(16) short Vs[64 * 64];      // 8 KB (dh-major)
    __shared__ __align__(16) short Ps[4][32 * KSTR]; // 18 KB

    const int t    = threadIdx.x;
    const int w    = t >> 6;
    const int lane = t & 63;
    const int quad = lane >> 4;
    const int l15  = lane & 15;
    const int QT   = (int)(gridDim.x - 1) - (int)blockIdx.x;  // heavy first
    const int h    = blockIdx.y;
    const int b    = blockIdx.z;
    const int bh   = b * NUM_HEADS + h;
    const short* qbase = Qg + (size_t)bh * SEQ * D_HEAD;
    const short* kbase = Kg + (size_t)bh * SEQ * D_HEAD;
    const short* vbase = Vg + (size_t)bh * D_HEAD * SEQ;
    const int q0 = QT * 128;
    const int qw = w * 32;

    // Q fragments: 2 strips of 16 rows (scale pre-folded into Wq/bq)
    s8v aq[2][2];
#pragma unroll
    for (int ms = 0; ms < 2; ++ms)
#pragma unroll
        for (int c = 0; c < 2; ++c)
            aq[ms][c] = *(const s8v*)&qbase[(size_t)(q0 + qw + ms * 16 + l15) * D_HEAD
                                            + c * 32 + quad * 8];

    f4v Oacc[2][4];
#pragma unroll
    for (int ms = 0; ms < 2; ++ms)
#pragma unroll
        for (int nt = 0; nt < 4; ++nt) Oacc[ms][nt] = (f4v){0.f, 0.f, 0.f, 0.f};
    float mrun[2][4], lrun[2][4];
#pragma unroll
    for (int ms = 0; ms < 2; ++ms)
#pragma unroll
        for (int r = 0; r < 4; ++r) { mrun[ms][r] = -INFINITY; lrun[ms][r] = 0.f; }

    const int jmax = 2 * QT + 1;
    for (int j = 0; j <= jmax; ++j) {
        __syncthreads();   // prev iter's Kb/Vs readers done
        // stage K tile [key][d] and V tile [dh][s], swizzled chunks, zero VALU
#pragma unroll
        for (int i = 0; i < 2; ++i) {
            const int cid = i * 256 + t;                 // this lane's LDS chunk
            const int row = cid >> 3, p = cid & 7, g = p ^ (row & 7);
            gld_lds16(&kbase[(size_t)(j * 64 + row) * D_HEAD + g * 8],
                      &Kb[(i * 256 + w * 64) * 8]);
            gld_lds16(&vbase[(size_t)row * SEQ + j * 64 + g * 8],
                      &Vs[(i * 256 + w * 64) * 8]);
        }
        __syncthreads();

        if (j == jmax && w < 2) continue;   // fully-masked tile for waves 0,1

        // S = Qhat @ K^T
        f4v S[2][4];
#pragma unroll
        for (int ms = 0; ms < 2; ++ms)
#pragma unroll
            for (int nt = 0; nt < 4; ++nt) S[ms][nt] = (f4v){0.f, 0.f, 0.f, 0.f};
#pragma unroll
        for (int c = 0; c < 2; ++c) {
            s8v bk[4];
#pragma unroll
            for (int nt = 0; nt < 4; ++nt) {
                const int row = nt * 16 + l15;
                bk[nt] = *(const s8v*)&Kb[row * 64 + (((c * 4 + quad) ^ (l15 & 7)) * 8)];
            }
#pragma unroll
            for (int ms = 0; ms < 2; ++ms)
#pragma unroll
                for (int nt = 0; nt < 4; ++nt)
                    S[ms][nt] = __builtin_amdgcn_mfma_f32_16x16x32_bf16(
                        aq[ms][c], bk[nt], S[ms][nt], 0, 0, 0);
        }

        // causal mask (two diagonal tiles per block)
        if (j >= 2 * QT) {
            const int koff = (j - 2 * QT) * 64;
#pragma unroll
            for (int ms = 0; ms < 2; ++ms)
#pragma unroll
                for (int nt = 0; nt < 4; ++nt)
#pragma unroll
                    for (int r = 0; r < 4; ++r)
                        if (koff + nt * 16 + l15 > qw + ms * 16 + quad * 4 + r)
                            S[ms][nt][r] = -INFINITY;
        }

        // online softmax (registers + 16-lane shfl reductions)
#pragma unroll
        for (int ms = 0; ms < 2; ++ms) {
            float mt[4], al[4], rs[4];
#pragma unroll
            for (int r = 0; r < 4; ++r)
                mt[r] = fmaxf(fmaxf(S[ms][0][r], S[ms][1][r]),
                              fmaxf(S[ms][2][r], S[ms][3][r]));
#pragma unroll
            for (int mk = 1; mk < 16; mk <<= 1)
#pragma unroll
                for (int r = 0; r < 4; ++r)
                    mt[r] = fmaxf(mt[r], __shfl_xor(mt[r], mk, 64));
#pragma unroll
            for (int r = 0; r < 4; ++r) {
                const float mn = fmaxf(mrun[ms][r], mt[r]);
                al[r] = exp2f((mrun[ms][r] - mn) * 1.44269504f);
                mrun[ms][r] = mn;
                rs[r] = 0.f;
            }
#pragma unroll
            for (int nt = 0; nt < 4; ++nt)
#pragma unroll
                for (int r = 0; r < 4; ++r) {
                    const float p = exp2f((S[ms][nt][r] - mrun[ms][r]) * 1.44269504f);
                    rs[r] += p;
                    Ps[w][(ms * 16 + quad * 4 + r) * KSTR + nt * 16 + l15] = to_bf(p);
                }
#pragma unroll
            for (int mk = 1; mk < 16; mk <<= 1)
#pragma unroll
                for (int r = 0; r < 4; ++r)
                    rs[r] += __shfl_xor(rs[r], mk, 64);
#pragma unroll
            for (int r = 0; r < 4; ++r) {
                lrun[ms][r] = al[r] * lrun[ms][r] + rs[r];
#pragma unroll
                for (int nt = 0; nt < 4; ++nt) Oacc[ms][nt][r] *= al[r];
            }
        }

        // O += P @ V   (Ps wave-private; lgkmcnt covers the RAW)
#pragma unroll
        for (int c = 0; c < 2; ++c) {
            s8v bv[4];
#pragma unroll
            for (int nt = 0; nt < 4; ++nt) {
                const int row = nt * 16 + l15;   // dh
                bv[nt] = *(const s8v*)&Vs[row * 64 + (((c * 4 + quad) ^ (l15 & 7)) * 8)];
            }
#pragma unroll
            for (int ms = 0; ms < 2; ++ms) {
                s8v ap = *(const s8v*)&Ps[w][(ms * 16 + l15) * KSTR + c * 32 + quad * 8];
#pragma unroll
                for (int nt = 0; nt < 4; ++nt)
                    Oacc[ms][nt] = __builtin_amdgcn_mfma_f32_16x16x32_bf16(
                        ap, bv[nt], Oacc[ms][nt], 0, 0, 0);
            }
        }
    }

    // normalize + write ctx bf16 [N, D_MODEL]
#pragma unroll
    for (int ms = 0; ms < 2; ++ms)
#pragma unroll
        for (int r = 0; r < 4; ++r) {
            const float inv = 1.f / lrun[ms][r];
            const int n = b * SEQ + q0 + qw + ms * 16 + quad * 4 + r;
            short* dst = &ctxb[(size_t)n * D_MODEL + h * D_HEAD + l15];
#pragma unroll
            for (int nt = 0; nt < 4; ++nt)
                dst[nt * 16] = to_bf(Oacc[ms][nt][r] * inv);
        }
}

// ---------------------------------------------------------------------------
extern "C" void kernel_launch(void* const* d_in, const int* in_sizes, int n_in,
                              void* d_out, int out_size, void* d_ws, size_t ws_size,
                              hipStream_t stream)
{
    const float* x  = (const float*)d_in[0];
    const float* Wq = (const float*)d_in[1];
    const float* bq = (const float*)d_in[2];
    const float* Wk = (const float*)d_in[3];
    const float* bk = (const float*)d_in[4];
    const float* Wv = (const float*)d_in[5];
    const float* bv = (const float*)d_in[6];
    const float* Wo = (const float*)d_in[7];
    const float* bo = (const float*)d_in[8];
    float* out = (float*)d_out;

    short* wsp = (short*)d_ws;
    const size_t MAT = (size_t)NROWS * D_MODEL;   // 4,194,304 elements
    short* Qb    = wsp;                 // bf16 [B,H,S,Dh]
    short* Kbg   = Qb + MAT;            // bf16 [B,H,S,Dh]
    short* Vtb   = Kbg + MAT;           // bf16 [B,H,Dh,S]
    short* ctxb  = Vtb + MAT;           // bf16 [N, D_MODEL]
    short* Xb    = ctxb + MAT;          // bf16 [N, D_MODEL]
    short* Wqkvb = Xb + MAT;            // bf16 [3072, 1024] (Wq pre-scaled)
    short* Wob   = Wqkvb + 3 * D_MODEL * D_MODEL;

    cvt_fused<<<8192, 256, 0, stream>>>(x, Wq, Wk, Wv, Wo, Xb, Wqkvb, Wob);

    gemm_bf16<<<dim3(3 * D_MODEL / 128, NROWS / 128), 256, 0, stream>>>(
        Xb, Wqkvb, bq, bk, bv, nullptr, Qb, Kbg, Vtb, 1);

    attn_mfma<<<dim3(SEQ / 128, NUM_HEADS, BATCH), 256, 0, stream>>>(
        Qb, Kbg, Vtb, ctxb);

    gemm_bf16<<<dim3(D_MODEL / 128, NROWS / 128), 256, 0, stream>>>(
        ctxb, Wob, bo, bo, bo, out, nullptr, nullptr, nullptr, 0);
}

// Round 5
// 238.006 us; speedup vs baseline: 11.0707x; 1.2401x over previous
//
#include <hip/hip_runtime.h>
#include <math.h>

#define D_MODEL 1024
#define NUM_HEADS 16
#define D_HEAD 64
#define SEQ 2048
#define BATCH 2
#define NROWS (BATCH * SEQ) /* 4096 */

typedef short s8v __attribute__((ext_vector_type(8)));   // 8 bf16 (4 VGPRs)
typedef float f4v __attribute__((ext_vector_type(4)));   // MFMA C/D

__device__ __forceinline__ short to_bf(float f) {
    union { float f; unsigned u; } x; x.f = f;
    unsigned r = x.u + 0x7fffu + ((x.u >> 16) & 1u);   // RNE
    return (short)(r >> 16);
}

// async global->LDS, 16 B/lane; LDS dest is wave-uniform base + lane*16
__device__ __forceinline__ void gld_lds16(const short* g, short* l) {
    __builtin_amdgcn_global_load_lds(
        (const __attribute__((address_space(1))) unsigned*)g,
        (__attribute__((address_space(3))) unsigned*)l, 16, 0, 0);
}

// ---------------------------------------------------------------------------
// fp32 -> bf16 convert. Wq segment pre-scaled by 1/sqrt(Dh) = 0.125.
// ---------------------------------------------------------------------------
__global__ __launch_bounds__(256) void cvt_fused(
    const float* __restrict__ x,  const float* __restrict__ Wq,
    const float* __restrict__ Wk, const float* __restrict__ Wv,
    const float* __restrict__ Wo,
    short* __restrict__ Xb, short* __restrict__ Wqkvb, short* __restrict__ Wob)
{
    const int NX = NROWS * D_MODEL / 4;
    const int NW = D_MODEL * D_MODEL / 4;
    int j = blockIdx.x * 256 + threadIdx.x;
    const float* src; short* dst; float sc = 1.f;
    if (j < NX)                 { src = x;  dst = Xb; }
    else if ((j -= NX) < NW)    { src = Wq; dst = Wqkvb; sc = 0.125f; }
    else if ((j -= NW) < NW)    { src = Wk; dst = Wqkvb + NW * 4; }
    else if ((j -= NW) < NW)    { src = Wv; dst = Wqkvb + NW * 8; }
    else                        { j -= NW; src = Wo; dst = Wob; }
    float4 v = ((const float4*)src)[j];
    short4 s = { to_bf(v.x * sc), to_bf(v.y * sc), to_bf(v.z * sc), to_bf(v.w * sc) };
    ((short4*)dst)[j] = s;
}

// ---------------------------------------------------------------------------
// bf16 MFMA GEMM (unchanged from R4): out = X @ W^T + bias. 128x128, BK=64.
// qkv_mode=1: bf16 Q [B,H,S,Dh], K [B,H,S,Dh], V^T [B,H,Dh,S] via LDS repack.
// qkv_mode=0: fp32 row-major [M,N].
// ---------------------------------------------------------------------------
__global__ __launch_bounds__(256) void gemm_bf16(
    const short* __restrict__ Xb, const short* __restrict__ Wb,
    const float* __restrict__ B0, const float* __restrict__ B1, const float* __restrict__ B2,
    float* __restrict__ Ofp,
    short* __restrict__ Q0, short* __restrict__ K1, short* __restrict__ V2,
    int qkv_mode)
{
    __shared__ __align__(16) short smem[18432];
    short* As = smem;
    short* Bs = smem + 8192;

    const int t    = threadIdx.x;
    const int w    = t >> 6;
    const int lane = t & 63;
    const int quad = lane >> 4;
    const int l15  = lane & 15;
    const int wm   = w & 1, wn = w >> 1;

    const int n0 = blockIdx.x * 128;
    const int m0 = blockIdx.y * 128;

    f4v acc[4][4];
#pragma unroll
    for (int i = 0; i < 4; ++i)
#pragma unroll
        for (int j = 0; j < 4; ++j) acc[i][j] = (f4v){0.f, 0.f, 0.f, 0.f};

    for (int k0 = 0; k0 < D_MODEL; k0 += 64) {
#pragma unroll
        for (int i = 0; i < 4; ++i) {
            const int cid = i * 256 + t;
            const int row = cid >> 3, kc = cid & 7;
            gld_lds16(&Xb[(size_t)(m0 + row) * D_MODEL + k0 + kc * 8],
                      &As[(i * 256 + w * 64) * 8]);
            gld_lds16(&Wb[(size_t)(n0 + row) * D_MODEL + k0 + kc * 8],
                      &Bs[(i * 256 + w * 64) * 8]);
        }
        __syncthreads();

#pragma unroll
        for (int c = 0; c < 2; ++c) {
            s8v af[4], bf[4];
#pragma unroll
            for (int mi = 0; mi < 4; ++mi)
                af[mi] = *(const s8v*)&As[(wm * 64 + mi * 16 + l15) * 64 + c * 32 + quad * 8];
#pragma unroll
            for (int ni = 0; ni < 4; ++ni)
                bf[ni] = *(const s8v*)&Bs[(wn * 64 + ni * 16 + l15) * 64 + c * 32 + quad * 8];
#pragma unroll
            for (int mi = 0; mi < 4; ++mi)
#pragma unroll
                for (int ni = 0; ni < 4; ++ni)
                    acc[mi][ni] = __builtin_amdgcn_mfma_f32_16x16x32_bf16(
                        af[mi], bf[ni], acc[mi][ni], 0, 0, 0);
        }
        __syncthreads();
    }

    if (!qkv_mode) {
#pragma unroll
        for (int ni = 0; ni < 4; ++ni) {
            const int col = n0 + wn * 64 + ni * 16 + l15;
            const float bv = B0[col];
#pragma unroll
            for (int mi = 0; mi < 4; ++mi)
#pragma unroll
                for (int r = 0; r < 4; ++r) {
                    const int row = m0 + wm * 64 + mi * 16 + quad * 4 + r;
                    Ofp[(size_t)row * D_MODEL + col] = acc[mi][ni][r] + bv;
                }
        }
        return;
    }

    const int sel = n0 >> 10;
    const float* bias = sel == 0 ? B0 : sel == 1 ? B1 : B2;
    short* out        = sel == 0 ? Q0 : sel == 1 ? K1 : V2;
    const float bsc   = sel == 0 ? 0.125f : 1.f;
    const int h0 = (n0 & 1023) >> 6;

#pragma unroll
    for (int ni = 0; ni < 4; ++ni) {
        const int col = wn * 64 + ni * 16 + l15;
        const float bv = bias[(n0 & 1023) + col] * bsc;
#pragma unroll
        for (int mi = 0; mi < 4; ++mi)
#pragma unroll
            for (int r = 0; r < 4; ++r) {
                const int row = wm * 64 + mi * 16 + quad * 4 + r;
                const short v = to_bf(acc[mi][ni][r] + bv);
                if (sel < 2) smem[row * 144 + col] = v;
                else         smem[col * 144 + row] = v;
            }
    }
    __syncthreads();

    const int rr = t >> 1, half = t & 1;
    const int bb = m0 >> 11, mloc = m0 & (SEQ - 1);
    const short* src = &smem[rr * 144 + half * 64];
    short* dst;
    if (sel < 2)
        dst = out + (((size_t)(bb * NUM_HEADS + h0 + half) * SEQ + (mloc + rr)) * D_HEAD);
    else
        dst = out + ((size_t)(bb * NUM_HEADS + h0 + (rr >> 6)) * D_HEAD + (rr & 63)) * SEQ
                  + mloc + half * 64;
#pragma unroll
    for (int i = 0; i < 8; ++i)
        ((int4*)dst)[i] = ((const int4*)src)[i];
}

// ---------------------------------------------------------------------------
// MFMA flash attention v3: 128-q x 128-key iterations, fixed-shift softmax,
// S computed TRANSPOSED (S^T = K·Q^T, swapped operands) so P stores are b64
// and l-sums are per-lane.  512 blocks: block c and c+256 share (b,h) and
// get complementary q-tiles (qt, 15-qt) -> every CU runs exactly 17 iters.
// K bf16 [B,H,S,Dh]; V^T bf16 [B,H,Dh,S]; XOR-swizzled 16B chunks in LDS.
// ---------------------------------------------------------------------------
__global__ __launch_bounds__(256) void attn_mfma(
    const short* __restrict__ Qg, const short* __restrict__ Kg,
    const short* __restrict__ Vg, short* __restrict__ ctxb)
{
    __shared__ __align__(16) short Kb[128 * 64];     // 16 KB  [key][d]
    __shared__ __align__(16) short Vs[64 * 128];     // 16 KB  [d][key]
    __shared__ __align__(16) short Ps[4][32 * 72];   // 18 KB  per-wave [q][key64]
    __shared__ float lbuf[4][36];

    const int t    = threadIdx.x;
    const int w    = t >> 6;
    const int lane = t & 63;
    const int quad = lane >> 4;
    const int l15  = lane & 15;

    // balanced pairing: blocks c and c+256 share (b,h), qt sums to 15
    const int bidx = blockIdx.x;
    const int p    = bidx & 255;
    const int bh   = p >> 3;
    const int pair = p & 7;
    const int qt   = (bidx < 256) ? pair : 15 - pair;
    const int b    = bh >> 4, h = bh & 15;

    const short* qbase = Qg + (size_t)bh * SEQ * D_HEAD;
    const short* kbase = Kg + (size_t)bh * SEQ * D_HEAD;
    const short* vbase = Vg + (size_t)bh * D_HEAD * SEQ;
    const int q0 = qt * 128;
    const int qw = w * 32;            // wave's query strip within block

    // Q fragments (B-operand layout: lane = query, regs = d). scale pre-folded.
    s8v aq[2][2];
#pragma unroll
    for (int ns = 0; ns < 2; ++ns)
#pragma unroll
        for (int c = 0; c < 2; ++c)
            aq[ns][c] = *(const s8v*)&qbase[(size_t)(q0 + qw + ns * 16 + l15) * D_HEAD
                                            + c * 32 + quad * 8];

    f4v Oacc[2][4];
#pragma unroll
    for (int ms = 0; ms < 2; ++ms)
#pragma unroll
        for (int nt = 0; nt < 4; ++nt) Oacc[ms][nt] = (f4v){0.f, 0.f, 0.f, 0.f};
    float lsum[2] = {0.f, 0.f};

    for (int j = 0; j <= qt; ++j) {
        __syncthreads();   // WAR: prev iter's readers done before DMA overwrite
        {
            const int k0 = j * 128;
#pragma unroll
            for (int i = 0; i < 4; ++i) {
                const int cid = i * 256 + w * 64 + lane;
                {   // K: 8 chunks/row; LDS[row][p] = G[row][p^(row&7)]
                    const int row = cid >> 3, pp = cid & 7, g = pp ^ (row & 7);
                    gld_lds16(&kbase[(size_t)(k0 + row) * D_HEAD + g * 8],
                              &Kb[(i * 256 + w * 64) * 8]);
                }
                {   // V^T: 16 chunks/row; swizzle low 3 bits
                    const int row = cid >> 4, pp = cid & 15;
                    const int g = (pp & 8) | ((pp & 7) ^ (row & 7));
                    gld_lds16(&vbase[(size_t)row * SEQ + k0 + g * 8],
                              &Vs[(i * 256 + w * 64) * 8]);
                }
            }
        }
        __syncthreads();   // RAW: compiler drains vmcnt before s_barrier

        const bool diag = (j == qt);

#pragma unroll
        for (int half = 0; half < 2; ++half) {
            // ---- S^T = K·Q^T for 64 keys; exp; P store (b64); lsum ----
#pragma unroll
            for (int mt = 0; mt < 4; ++mt) {
                const int krow = half * 64 + mt * 16 + l15;
                s8v ka0 = *(const s8v*)&Kb[(krow * 8 + (quad ^ (l15 & 7))) * 8];
                s8v ka1 = *(const s8v*)&Kb[(krow * 8 + ((4 + quad) ^ (l15 & 7))) * 8];
#pragma unroll
                for (int ns = 0; ns < 2; ++ns) {
                    f4v st = (f4v){0.f, 0.f, 0.f, 0.f};
                    st = __builtin_amdgcn_mfma_f32_16x16x32_bf16(ka0, aq[ns][0], st, 0, 0, 0);
                    st = __builtin_amdgcn_mfma_f32_16x16x32_bf16(ka1, aq[ns][1], st, 0, 0, 0);
                    if (diag) {
#pragma unroll
                        for (int r = 0; r < 4; ++r)
                            if (half * 64 + mt * 16 + quad * 4 + r > qw + ns * 16 + l15)
                                st[r] = -INFINITY;
                    }
                    short4 pk;
#pragma unroll
                    for (int r = 0; r < 4; ++r) {
                        const float pv = exp2f(fmaf(st[r], 1.44269504f, -20.f));
                        lsum[ns] += pv;
                        ((short*)&pk)[r] = to_bf(pv);
                    }
                    *(short4*)&Ps[w][(ns * 16 + l15) * 72 + mt * 16 + quad * 4] = pk;
                }
            }
            // ---- O += P @ V for these 64 keys (Ps wave-private, in-order DS) ----
#pragma unroll
            for (int ms = 0; ms < 2; ++ms)
#pragma unroll
                for (int c2 = 0; c2 < 2; ++c2) {
                    s8v ap = *(const s8v*)&Ps[w][(ms * 16 + l15) * 72 + c2 * 32 + quad * 8];
#pragma unroll
                    for (int nt = 0; nt < 4; ++nt) {
                        const int vrow = nt * 16 + l15;
                        const int g = (half * 2 + c2) * 4 + quad;
                        const int pos = (g & 8) | ((g & 7) ^ (l15 & 7));
                        s8v bv = *(const s8v*)&Vs[(vrow * 16 + pos) * 8];
                        Oacc[ms][nt] = __builtin_amdgcn_mfma_f32_16x16x32_bf16(
                            ap, bv, Oacc[ms][nt], 0, 0, 0);
                    }
                }
        }
    }

    // ---- final l reduction (once), normalize, store ctx bf16 ----
#pragma unroll
    for (int ns = 0; ns < 2; ++ns) {
        lsum[ns] += __shfl_xor(lsum[ns], 16, 64);
        lsum[ns] += __shfl_xor(lsum[ns], 32, 64);
    }
    if (quad == 0) { lbuf[w][l15] = lsum[0]; lbuf[w][16 + l15] = lsum[1]; }
    // wave-private lbuf: same-wave DS ordering suffices
#pragma unroll
    for (int ms = 0; ms < 2; ++ms) {
        float4 lv = *(float4*)&lbuf[w][ms * 16 + quad * 4];
        const float li[4] = {lv.x, lv.y, lv.z, lv.w};
#pragma unroll
        for (int r = 0; r < 4; ++r) {
            const float inv = 1.f / li[r];
            const int n = b * SEQ + q0 + qw + ms * 16 + quad * 4 + r;
            short* dst = &ctxb[(size_t)n * D_MODEL + h * D_HEAD + l15];
#pragma unroll
            for (int nt = 0; nt < 4; ++nt)
                dst[nt * 16] = to_bf(Oacc[ms][nt][r] * inv);
        }
    }
}

// ---------------------------------------------------------------------------
extern "C" void kernel_launch(void* const* d_in, const int* in_sizes, int n_in,
                              void* d_out, int out_size, void* d_ws, size_t ws_size,
                              hipStream_t stream)
{
    const float* x  = (const float*)d_in[0];
    const float* Wq = (const float*)d_in[1];
    const float* bq = (const float*)d_in[2];
    const float* Wk = (const float*)d_in[3];
    const float* bk = (const float*)d_in[4];
    const float* Wv = (const float*)d_in[5];
    const float* bv = (const float*)d_in[6];
    const float* Wo = (const float*)d_in[7];
    const float* bo = (const float*)d_in[8];
    float* out = (float*)d_out;

    short* wsp = (short*)d_ws;
    const size_t MAT = (size_t)NROWS * D_MODEL;
    short* Qb    = wsp;                 // bf16 [B,H,S,Dh]
    short* Kbg   = Qb + MAT;            // bf16 [B,H,S,Dh]
    short* Vtb   = Kbg + MAT;           // bf16 [B,H,Dh,S]
    short* ctxb  = Vtb + MAT;           // bf16 [N, D_MODEL]
    short* Xb    = ctxb + MAT;          // bf16 [N, D_MODEL]
    short* Wqkvb = Xb + MAT;            // bf16 [3072, 1024] (Wq pre-scaled)
    short* Wob   = Wqkvb + 3 * D_MODEL * D_MODEL;

    cvt_fused<<<8192, 256, 0, stream>>>(x, Wq, Wk, Wv, Wo, Xb, Wqkvb, Wob);

    gemm_bf16<<<dim3(3 * D_MODEL / 128, NROWS / 128), 256, 0, stream>>>(
        Xb, Wqkvb, bq, bk, bv, nullptr, Qb, Kbg, Vtb, 1);

    attn_mfma<<<dim3(512), 256, 0, stream>>>(Qb, Kbg, Vtb, ctxb);

    gemm_bf16<<<dim3(D_MODEL / 128, NROWS / 128), 256, 0, stream>>>(
        ctxb, Wob, bo, bo, bo, out, nullptr, nullptr, nullptr, 0);
}

// Round 6
// 234.388 us; speedup vs baseline: 11.2416x; 1.0154x over previous
//
#include <hip/hip_runtime.h>
#include <math.h>

#define D_MODEL 1024
#define NUM_HEADS 16
#define D_HEAD 64
#define SEQ 2048
#define BATCH 2
#define NROWS (BATCH * SEQ) /* 4096 */

typedef short s8v __attribute__((ext_vector_type(8)));   // 8 bf16 (4 VGPRs)
typedef float f4v __attribute__((ext_vector_type(4)));   // MFMA C/D

__device__ __forceinline__ short to_bf(float f) {
    union { float f; unsigned u; } x; x.f = f;
    unsigned r = x.u + 0x7fffu + ((x.u >> 16) & 1u);   // RNE
    return (short)(r >> 16);
}

// async global->LDS, 16 B/lane; LDS dest is wave-uniform base + lane*16
__device__ __forceinline__ void gld_lds16(const short* g, short* l) {
    __builtin_amdgcn_global_load_lds(
        (const __attribute__((address_space(1))) unsigned*)g,
        (__attribute__((address_space(3))) unsigned*)l, 16, 0, 0);
}

// Q pre-scale: 1/sqrt(Dh) * log2(e)  -> S leaves MFMA in exp2 domain
#define QSCALE 0.180336880f

// ---------------------------------------------------------------------------
// fp32 -> bf16 convert. Wq segment pre-scaled by QSCALE.
// ---------------------------------------------------------------------------
__global__ __launch_bounds__(256) void cvt_fused(
    const float* __restrict__ x,  const float* __restrict__ Wq,
    const float* __restrict__ Wk, const float* __restrict__ Wv,
    const float* __restrict__ Wo,
    short* __restrict__ Xb, short* __restrict__ Wqkvb, short* __restrict__ Wob)
{
    const int NX = NROWS * D_MODEL / 4;
    const int NW = D_MODEL * D_MODEL / 4;
    int j = blockIdx.x * 256 + threadIdx.x;
    const float* src; short* dst; float sc = 1.f;
    if (j < NX)                 { src = x;  dst = Xb; }
    else if ((j -= NX) < NW)    { src = Wq; dst = Wqkvb; sc = QSCALE; }
    else if ((j -= NW) < NW)    { src = Wk; dst = Wqkvb + NW * 4; }
    else if ((j -= NW) < NW)    { src = Wv; dst = Wqkvb + NW * 8; }
    else                        { j -= NW; src = Wo; dst = Wob; }
    float4 v = ((const float4*)src)[j];
    short4 s = { to_bf(v.x * sc), to_bf(v.y * sc), to_bf(v.z * sc), to_bf(v.w * sc) };
    ((short4*)dst)[j] = s;
}

// ---------------------------------------------------------------------------
// bf16 MFMA GEMM: out = X @ W^T + bias. 128x128, BK=64.
// qkv_mode=1: bf16 Q [B,H,S,Dh], K [B,H,S,Dh], V^T [B,H,Dh,S] via LDS repack.
//   Q bias scaled by QSCALE (Wq pre-scaled at cvt).
// qkv_mode=0: fp32 row-major [M,N].
// ---------------------------------------------------------------------------
__global__ __launch_bounds__(256) void gemm_bf16(
    const short* __restrict__ Xb, const short* __restrict__ Wb,
    const float* __restrict__ B0, const float* __restrict__ B1, const float* __restrict__ B2,
    float* __restrict__ Ofp,
    short* __restrict__ Q0, short* __restrict__ K1, short* __restrict__ V2,
    int qkv_mode)
{
    __shared__ __align__(16) short smem[18432];
    short* As = smem;
    short* Bs = smem + 8192;

    const int t    = threadIdx.x;
    const int w    = t >> 6;
    const int lane = t & 63;
    const int quad = lane >> 4;
    const int l15  = lane & 15;
    const int wm   = w & 1, wn = w >> 1;

    const int n0 = blockIdx.x * 128;
    const int m0 = blockIdx.y * 128;

    f4v acc[4][4];
#pragma unroll
    for (int i = 0; i < 4; ++i)
#pragma unroll
        for (int j = 0; j < 4; ++j) acc[i][j] = (f4v){0.f, 0.f, 0.f, 0.f};

    for (int k0 = 0; k0 < D_MODEL; k0 += 64) {
#pragma unroll
        for (int i = 0; i < 4; ++i) {
            const int cid = i * 256 + t;
            const int row = cid >> 3, kc = cid & 7;
            gld_lds16(&Xb[(size_t)(m0 + row) * D_MODEL + k0 + kc * 8],
                      &As[(i * 256 + w * 64) * 8]);
            gld_lds16(&Wb[(size_t)(n0 + row) * D_MODEL + k0 + kc * 8],
                      &Bs[(i * 256 + w * 64) * 8]);
        }
        __syncthreads();

#pragma unroll
        for (int c = 0; c < 2; ++c) {
            s8v af[4], bf[4];
#pragma unroll
            for (int mi = 0; mi < 4; ++mi)
                af[mi] = *(const s8v*)&As[(wm * 64 + mi * 16 + l15) * 64 + c * 32 + quad * 8];
#pragma unroll
            for (int ni = 0; ni < 4; ++ni)
                bf[ni] = *(const s8v*)&Bs[(wn * 64 + ni * 16 + l15) * 64 + c * 32 + quad * 8];
#pragma unroll
            for (int mi = 0; mi < 4; ++mi)
#pragma unroll
                for (int ni = 0; ni < 4; ++ni)
                    acc[mi][ni] = __builtin_amdgcn_mfma_f32_16x16x32_bf16(
                        af[mi], bf[ni], acc[mi][ni], 0, 0, 0);
        }
        __syncthreads();
    }

    if (!qkv_mode) {
#pragma unroll
        for (int ni = 0; ni < 4; ++ni) {
            const int col = n0 + wn * 64 + ni * 16 + l15;
            const float bv = B0[col];
#pragma unroll
            for (int mi = 0; mi < 4; ++mi)
#pragma unroll
                for (int r = 0; r < 4; ++r) {
                    const int row = m0 + wm * 64 + mi * 16 + quad * 4 + r;
                    Ofp[(size_t)row * D_MODEL + col] = acc[mi][ni][r] + bv;
                }
        }
        return;
    }

    const int sel = n0 >> 10;
    const float* bias = sel == 0 ? B0 : sel == 1 ? B1 : B2;
    short* out        = sel == 0 ? Q0 : sel == 1 ? K1 : V2;
    const float bsc   = sel == 0 ? QSCALE : 1.f;
    const int h0 = (n0 & 1023) >> 6;

#pragma unroll
    for (int ni = 0; ni < 4; ++ni) {
        const int col = wn * 64 + ni * 16 + l15;
        const float bv = bias[(n0 & 1023) + col] * bsc;
#pragma unroll
        for (int mi = 0; mi < 4; ++mi)
#pragma unroll
            for (int r = 0; r < 4; ++r) {
                const int row = wm * 64 + mi * 16 + quad * 4 + r;
                const short v = to_bf(acc[mi][ni][r] + bv);
                if (sel < 2) smem[row * 144 + col] = v;
                else         smem[col * 144 + row] = v;
            }
    }
    __syncthreads();

    const int rr = t >> 1, half = t & 1;
    const int bb = m0 >> 11, mloc = m0 & (SEQ - 1);
    const short* src = &smem[rr * 144 + half * 64];
    short* dst;
    if (sel < 2)
        dst = out + (((size_t)(bb * NUM_HEADS + h0 + half) * SEQ + (mloc + rr)) * D_HEAD);
    else
        dst = out + ((size_t)(bb * NUM_HEADS + h0 + (rr >> 6)) * D_HEAD + (rr & 63)) * SEQ
                  + mloc + half * 64;
#pragma unroll
    for (int i = 0; i < 8; ++i)
        ((int4*)dst)[i] = ((const int4*)src)[i];
}

// ---------------------------------------------------------------------------
// MFMA flash attention v4: S in exp2 domain (log2e folded into Q), no shift
// (2^c cancels in O/l), truncating bf16 pack (v_perm), hoisted PV B-frags.
// 512 blocks: c and c+256 share (b,h), complementary qt -> 17 iters/CU.
// ---------------------------------------------------------------------------
__global__ __launch_bounds__(256) void attn_mfma(
    const short* __restrict__ Qg, const short* __restrict__ Kg,
    const short* __restrict__ Vg, short* __restrict__ ctxb)
{
    __shared__ __align__(16) short Kb[128 * 64];     // 16 KB  [key][d]
    __shared__ __align__(16) short Vs[64 * 128];     // 16 KB  [d][key]
    __shared__ __align__(16) short Ps[4][32 * 72];   // 18 KB  per-wave [q][key64]
    __shared__ float lbuf[4][36];

    const int t    = threadIdx.x;
    const int w    = t >> 6;
    const int lane = t & 63;
    const int quad = lane >> 4;
    const int l15  = lane & 15;

    const int bidx = blockIdx.x;
    const int p    = bidx & 255;
    const int bh   = p >> 3;
    const int pair = p & 7;
    const int qt   = (bidx < 256) ? pair : 15 - pair;
    const int b    = bh >> 4, h = bh & 15;

    const short* qbase = Qg + (size_t)bh * SEQ * D_HEAD;
    const short* kbase = Kg + (size_t)bh * SEQ * D_HEAD;
    const short* vbase = Vg + (size_t)bh * D_HEAD * SEQ;
    const int q0 = qt * 128;
    const int qw = w * 32;

    // Q fragments (B-operand layout: lane = query, regs = d). QSCALE pre-folded.
    s8v aq[2][2];
#pragma unroll
    for (int ns = 0; ns < 2; ++ns)
#pragma unroll
        for (int c = 0; c < 2; ++c)
            aq[ns][c] = *(const s8v*)&qbase[(size_t)(q0 + qw + ns * 16 + l15) * D_HEAD
                                            + c * 32 + quad * 8];

    f4v Oacc[2][4];
#pragma unroll
    for (int ms = 0; ms < 2; ++ms)
#pragma unroll
        for (int nt = 0; nt < 4; ++nt) Oacc[ms][nt] = (f4v){0.f, 0.f, 0.f, 0.f};
    float lsum[2] = {0.f, 0.f};

    for (int j = 0; j <= qt; ++j) {
        __syncthreads();   // WAR: prev iter's readers done before DMA overwrite
        {
            const int k0 = j * 128;
#pragma unroll
            for (int i = 0; i < 4; ++i) {
                const int cid = i * 256 + w * 64 + lane;
                {   // K: 8 chunks/row; LDS[row][p] = G[row][p^(row&7)]
                    const int row = cid >> 3, pp = cid & 7, g = pp ^ (row & 7);
                    gld_lds16(&kbase[(size_t)(k0 + row) * D_HEAD + g * 8],
                              &Kb[(i * 256 + w * 64) * 8]);
                }
                {   // V^T: 16 chunks/row; swizzle low 3 bits
                    const int row = cid >> 4, pp = cid & 15;
                    const int g = (pp & 8) | ((pp & 7) ^ (row & 7));
                    gld_lds16(&vbase[(size_t)row * SEQ + k0 + g * 8],
                              &Vs[(i * 256 + w * 64) * 8]);
                }
            }
        }
        __syncthreads();   // RAW: compiler drains vmcnt before s_barrier

        const bool diag = (j == qt);

#pragma unroll
        for (int half = 0; half < 2; ++half) {
            // ---- S^T = K·Q^T (exp2 domain); exp; truncate-pack; b64 store ----
#pragma unroll
            for (int mt = 0; mt < 4; ++mt) {
                const int krow = half * 64 + mt * 16 + l15;
                s8v ka0 = *(const s8v*)&Kb[(krow * 8 + (quad ^ (l15 & 7))) * 8];
                s8v ka1 = *(const s8v*)&Kb[(krow * 8 + ((4 + quad) ^ (l15 & 7))) * 8];
#pragma unroll
                for (int ns = 0; ns < 2; ++ns) {
                    f4v st = (f4v){0.f, 0.f, 0.f, 0.f};
                    st = __builtin_amdgcn_mfma_f32_16x16x32_bf16(ka0, aq[ns][0], st, 0, 0, 0);
                    st = __builtin_amdgcn_mfma_f32_16x16x32_bf16(ka1, aq[ns][1], st, 0, 0, 0);
                    if (diag) {
#pragma unroll
                        for (int r = 0; r < 4; ++r)
                            if (half * 64 + mt * 16 + quad * 4 + r > qw + ns * 16 + l15)
                                st[r] = -INFINITY;
                    }
                    float e0 = exp2f(st[0]), e1 = exp2f(st[1]);
                    float e2 = exp2f(st[2]), e3 = exp2f(st[3]);
                    lsum[ns] += (e0 + e1) + (e2 + e3);
                    int2 pk;
                    pk.x = (int)((__float_as_uint(e0) >> 16) | (__float_as_uint(e1) & 0xffff0000u));
                    pk.y = (int)((__float_as_uint(e2) >> 16) | (__float_as_uint(e3) & 0xffff0000u));
                    *(int2*)&Ps[w][(ns * 16 + l15) * 72 + mt * 16 + quad * 4] = pk;
                }
            }
            // ---- O += P @ V (hoisted B-frags; Ps wave-private, in-order DS) ----
#pragma unroll
            for (int c2 = 0; c2 < 2; ++c2) {
                s8v ap0 = *(const s8v*)&Ps[w][l15 * 72 + c2 * 32 + quad * 8];
                s8v ap1 = *(const s8v*)&Ps[w][(16 + l15) * 72 + c2 * 32 + quad * 8];
                const int g = (half * 2 + c2) * 4 + quad;
                const int pos = (g & 8) | ((g & 7) ^ (l15 & 7));
                s8v bv[4];
#pragma unroll
                for (int nt = 0; nt < 4; ++nt)
                    bv[nt] = *(const s8v*)&Vs[((nt * 16 + l15) * 16 + pos) * 8];
#pragma unroll
                for (int nt = 0; nt < 4; ++nt) {
                    Oacc[0][nt] = __builtin_amdgcn_mfma_f32_16x16x32_bf16(
                        ap0, bv[nt], Oacc[0][nt], 0, 0, 0);
                    Oacc[1][nt] = __builtin_amdgcn_mfma_f32_16x16x32_bf16(
                        ap1, bv[nt], Oacc[1][nt], 0, 0, 0);
                }
            }
        }
    }

    // ---- final l reduction (once), normalize, store ctx bf16 ----
#pragma unroll
    for (int ns = 0; ns < 2; ++ns) {
        lsum[ns] += __shfl_xor(lsum[ns], 16, 64);
        lsum[ns] += __shfl_xor(lsum[ns], 32, 64);
    }
    if (quad == 0) { lbuf[w][l15] = lsum[0]; lbuf[w][16 + l15] = lsum[1]; }
    // wave-private lbuf: same-wave DS ordering suffices
#pragma unroll
    for (int ms = 0; ms < 2; ++ms) {
        float4 lv = *(float4*)&lbuf[w][ms * 16 + quad * 4];
        const float li[4] = {lv.x, lv.y, lv.z, lv.w};
#pragma unroll
        for (int r = 0; r < 4; ++r) {
            const float inv = 1.f / li[r];
            const int n = b * SEQ + q0 + qw + ms * 16 + quad * 4 + r;
            short* dst = &ctxb[(size_t)n * D_MODEL + h * D_HEAD + l15];
#pragma unroll
            for (int nt = 0; nt < 4; ++nt)
                dst[nt * 16] = to_bf(Oacc[ms][nt][r] * inv);
        }
    }
}

// ---------------------------------------------------------------------------
extern "C" void kernel_launch(void* const* d_in, const int* in_sizes, int n_in,
                              void* d_out, int out_size, void* d_ws, size_t ws_size,
                              hipStream_t stream)
{
    const float* x  = (const float*)d_in[0];
    const float* Wq = (const float*)d_in[1];
    const float* bq = (const float*)d_in[2];
    const float* Wk = (const float*)d_in[3];
    const float* bk = (const float*)d_in[4];
    const float* Wv = (const float*)d_in[5];
    const float* bv = (const float*)d_in[6];
    const float* Wo = (const float*)d_in[7];
    const float* bo = (const float*)d_in[8];
    float* out = (float*)d_out;

    short* wsp = (short*)d_ws;
    const size_t MAT = (size_t)NROWS * D_MODEL;
    short* Qb    = wsp;                 // bf16 [B,H,S,Dh] (exp2-domain scale)
    short* Kbg   = Qb + MAT;            // bf16 [B,H,S,Dh]
    short* Vtb   = Kbg + MAT;           // bf16 [B,H,Dh,S]
    short* ctxb  = Vtb + MAT;           // bf16 [N, D_MODEL]
    short* Xb    = ctxb + MAT;          // bf16 [N, D_MODEL]
    short* Wqkvb = Xb + MAT;            // bf16 [3072, 1024] (Wq pre-scaled)
    short* Wob   = Wqkvb + 3 * D_MODEL * D_MODEL;

    cvt_fused<<<8192, 256, 0, stream>>>(x, Wq, Wk, Wv, Wo, Xb, Wqkvb, Wob);

    gemm_bf16<<<dim3(3 * D_MODEL / 128, NROWS / 128), 256, 0, stream>>>(
        Xb, Wqkvb, bq, bk, bv, nullptr, Qb, Kbg, Vtb, 1);

    attn_mfma<<<dim3(512), 256, 0, stream>>>(Qb, Kbg, Vtb, ctxb);

    gemm_bf16<<<dim3(D_MODEL / 128, NROWS / 128), 256, 0, stream>>>(
        ctxb, Wob, bo, bo, bo, out, nullptr, nullptr, nullptr, 0);
}

// Round 7
// 215.518 us; speedup vs baseline: 12.2259x; 1.0876x over previous
//
#include <hip/hip_runtime.h>
#include <math.h>

#define D_MODEL 1024
#define NUM_HEADS 16
#define D_HEAD 64
#define SEQ 2048
#define BATCH 2
#define NROWS (BATCH * SEQ) /* 4096 */

typedef short s8v __attribute__((ext_vector_type(8)));   // 8 bf16 (4 VGPRs)
typedef float f4v __attribute__((ext_vector_type(4)));   // MFMA C/D

__device__ __forceinline__ short to_bf(float f) {
    union { float f; unsigned u; } x; x.f = f;
    unsigned r = x.u + 0x7fffu + ((x.u >> 16) & 1u);   // RNE
    return (short)(r >> 16);
}

// async global->LDS, 16 B/lane; LDS dest is wave-uniform base + lane*16
__device__ __forceinline__ void gld_lds16(const short* g, short* l) {
    __builtin_amdgcn_global_load_lds(
        (const __attribute__((address_space(1))) unsigned*)g,
        (__attribute__((address_space(3))) unsigned*)l, 16, 0, 0);
}

// Q pre-scale: 1/sqrt(Dh) * log2(e)  -> S leaves MFMA in exp2 domain
#define QSCALE 0.180336880f

// ---------------------------------------------------------------------------
// fp32 -> bf16 convert. Wq segment pre-scaled by QSCALE.
// ---------------------------------------------------------------------------
__global__ __launch_bounds__(256) void cvt_fused(
    const float* __restrict__ x,  const float* __restrict__ Wq,
    const float* __restrict__ Wk, const float* __restrict__ Wv,
    const float* __restrict__ Wo,
    short* __restrict__ Xb, short* __restrict__ Wqkvb, short* __restrict__ Wob)
{
    const int NX = NROWS * D_MODEL / 4;
    const int NW = D_MODEL * D_MODEL / 4;
    int j = blockIdx.x * 256 + threadIdx.x;
    const float* src; short* dst; float sc = 1.f;
    if (j < NX)                 { src = x;  dst = Xb; }
    else if ((j -= NX) < NW)    { src = Wq; dst = Wqkvb; sc = QSCALE; }
    else if ((j -= NW) < NW)    { src = Wk; dst = Wqkvb + NW * 4; }
    else if ((j -= NW) < NW)    { src = Wv; dst = Wqkvb + NW * 8; }
    else                        { j -= NW; src = Wo; dst = Wob; }
    float4 v = ((const float4*)src)[j];
    short4 s = { to_bf(v.x * sc), to_bf(v.y * sc), to_bf(v.z * sc), to_bf(v.w * sc) };
    ((short4*)dst)[j] = s;
}

// ---------------------------------------------------------------------------
// bf16 MFMA GEMM: out = X @ W^T + bias. 128x128, BK=64, 4 waves.
// XOR-swizzled LDS chunks: slot (row,p) holds global chunk p^(row&7) ->
// fragment ds_read_b128 spreads over all 32 banks (2 lanes/bank = free).
// qkv_mode=1: bf16 Q [B,H,S,Dh], K [B,H,S,Dh], V^T [B,H,Dh,S] via LDS repack.
// qkv_mode=0: fp32 row-major [M,N].
// ---------------------------------------------------------------------------
__global__ __launch_bounds__(256) void gemm_bf16(
    const short* __restrict__ Xb, const short* __restrict__ Wb,
    const float* __restrict__ B0, const float* __restrict__ B1, const float* __restrict__ B2,
    float* __restrict__ Ofp,
    short* __restrict__ Q0, short* __restrict__ K1, short* __restrict__ V2,
    int qkv_mode)
{
    __shared__ __align__(16) short smem[18432];
    short* As = smem;
    short* Bs = smem + 8192;

    const int t    = threadIdx.x;
    const int w    = t >> 6;
    const int lane = t & 63;
    const int quad = lane >> 4;
    const int l15  = lane & 15;
    const int wm   = w & 1, wn = w >> 1;

    const int n0 = blockIdx.x * 128;
    const int m0 = blockIdx.y * 128;

    f4v acc[4][4];
#pragma unroll
    for (int i = 0; i < 4; ++i)
#pragma unroll
        for (int j = 0; j < 4; ++j) acc[i][j] = (f4v){0.f, 0.f, 0.f, 0.f};

    for (int k0 = 0; k0 < D_MODEL; k0 += 64) {
#pragma unroll
        for (int i = 0; i < 4; ++i) {
            const int cid = i * 256 + t;
            const int row = cid >> 3, kc = cid & 7, g = kc ^ (row & 7);
            gld_lds16(&Xb[(size_t)(m0 + row) * D_MODEL + k0 + g * 8],
                      &As[(i * 256 + w * 64) * 8]);
            gld_lds16(&Wb[(size_t)(n0 + row) * D_MODEL + k0 + g * 8],
                      &Bs[(i * 256 + w * 64) * 8]);
        }
        __syncthreads();

#pragma unroll
        for (int c = 0; c < 2; ++c) {
            s8v af[4], bf[4];
            const int pos = ((c * 4 + quad) ^ (l15 & 7)) * 8;
#pragma unroll
            for (int mi = 0; mi < 4; ++mi)
                af[mi] = *(const s8v*)&As[(wm * 64 + mi * 16 + l15) * 64 + pos];
#pragma unroll
            for (int ni = 0; ni < 4; ++ni)
                bf[ni] = *(const s8v*)&Bs[(wn * 64 + ni * 16 + l15) * 64 + pos];
#pragma unroll
            for (int mi = 0; mi < 4; ++mi)
#pragma unroll
                for (int ni = 0; ni < 4; ++ni)
                    acc[mi][ni] = __builtin_amdgcn_mfma_f32_16x16x32_bf16(
                        af[mi], bf[ni], acc[mi][ni], 0, 0, 0);
        }
        __syncthreads();
    }

    if (!qkv_mode) {
#pragma unroll
        for (int ni = 0; ni < 4; ++ni) {
            const int col = n0 + wn * 64 + ni * 16 + l15;
            const float bv = B0[col];
#pragma unroll
            for (int mi = 0; mi < 4; ++mi)
#pragma unroll
                for (int r = 0; r < 4; ++r) {
                    const int row = m0 + wm * 64 + mi * 16 + quad * 4 + r;
                    Ofp[(size_t)row * D_MODEL + col] = acc[mi][ni][r] + bv;
                }
        }
        return;
    }

    const int sel = n0 >> 10;
    const float* bias = sel == 0 ? B0 : sel == 1 ? B1 : B2;
    short* out        = sel == 0 ? Q0 : sel == 1 ? K1 : V2;
    const float bsc   = sel == 0 ? QSCALE : 1.f;
    const int h0 = (n0 & 1023) >> 6;

#pragma unroll
    for (int ni = 0; ni < 4; ++ni) {
        const int col = wn * 64 + ni * 16 + l15;
        const float bv = bias[(n0 & 1023) + col] * bsc;
#pragma unroll
        for (int mi = 0; mi < 4; ++mi)
#pragma unroll
            for (int r = 0; r < 4; ++r) {
                const int row = wm * 64 + mi * 16 + quad * 4 + r;
                const short v = to_bf(acc[mi][ni][r] + bv);
                if (sel < 2) smem[row * 144 + col] = v;
                else         smem[col * 144 + row] = v;
            }
    }
    __syncthreads();

    const int rr = t >> 1, half = t & 1;
    const int bb = m0 >> 11, mloc = m0 & (SEQ - 1);
    const short* src = &smem[rr * 144 + half * 64];
    short* dst;
    if (sel < 2)
        dst = out + (((size_t)(bb * NUM_HEADS + h0 + half) * SEQ + (mloc + rr)) * D_HEAD);
    else
        dst = out + ((size_t)(bb * NUM_HEADS + h0 + (rr >> 6)) * D_HEAD + (rr & 63)) * SEQ
                  + mloc + half * 64;
#pragma unroll
    for (int i = 0; i < 8; ++i)
        ((int4*)dst)[i] = ((const int4*)src)[i];
}

// ---------------------------------------------------------------------------
// MFMA flash attention v5: key-split flash-decoding. 1024 blocks =
// 2 key-segments x 2 qt-halves x 256 (bh,pair).  Segment s handles key
// tiles j ≡ s (mod 2); fixed-shift softmax -> partials combine by ADDITION.
// Writes unnormalized O (bf16) + l (fp32) partials; combine kernel divides.
// Balanced: each CU's 4 blocks total exactly 17 tile-iters.
// ---------------------------------------------------------------------------
__global__ __launch_bounds__(256) void attn_mfma(
    const short* __restrict__ Qg, const short* __restrict__ Kg,
    const short* __restrict__ Vg,
    short* __restrict__ Op0, short* __restrict__ Op1, float* __restrict__ Lp)
{
    __shared__ __align__(16) short Kb[128 * 64];     // 16 KB  [key][d]
    __shared__ __align__(16) short Vs[64 * 128];     // 16 KB  [d][key]
    __shared__ __align__(16) short Ps[4][32 * 72];   // 18 KB  per-wave [q][key64]

    const int t    = threadIdx.x;
    const int w    = t >> 6;
    const int lane = t & 63;
    const int quad = lane >> 4;
    const int l15  = lane & 15;

    const int bidx = blockIdx.x;
    const int seg  = bidx >> 9;               // key parity
    const int p    = bidx & 255;
    const int bh   = p >> 3;
    const int pair = p & 7;
    const int qt   = ((bidx >> 8) & 1) ? 15 - pair : pair;
    const int b    = bh >> 4, h = bh & 15;

    const short* qbase = Qg + (size_t)bh * SEQ * D_HEAD;
    const short* kbase = Kg + (size_t)bh * SEQ * D_HEAD;
    const short* vbase = Vg + (size_t)bh * D_HEAD * SEQ;
    const int q0 = qt * 128;
    const int qw = w * 32;

    // Q fragments (B-operand layout: lane = query, regs = d). QSCALE pre-folded.
    s8v aq[2][2];
#pragma unroll
    for (int ns = 0; ns < 2; ++ns)
#pragma unroll
        for (int c = 0; c < 2; ++c)
            aq[ns][c] = *(const s8v*)&qbase[(size_t)(q0 + qw + ns * 16 + l15) * D_HEAD
                                            + c * 32 + quad * 8];

    f4v Oacc[2][4];
#pragma unroll
    for (int ms = 0; ms < 2; ++ms)
#pragma unroll
        for (int nt = 0; nt < 4; ++nt) Oacc[ms][nt] = (f4v){0.f, 0.f, 0.f, 0.f};
    float lsum[2] = {0.f, 0.f};

    for (int j = seg; j <= qt; j += 2) {
        __syncthreads();   // WAR: prev iter's readers done before DMA overwrite
        {
            const int k0 = j * 128;
#pragma unroll
            for (int i = 0; i < 4; ++i) {
                const int cid = i * 256 + w * 64 + lane;
                {   // K: 8 chunks/row; LDS[row][p] = G[row][p^(row&7)]
                    const int row = cid >> 3, pp = cid & 7, g = pp ^ (row & 7);
                    gld_lds16(&kbase[(size_t)(k0 + row) * D_HEAD + g * 8],
                              &Kb[(i * 256 + w * 64) * 8]);
                }
                {   // V^T: 16 chunks/row; swizzle low 3 bits
                    const int row = cid >> 4, pp = cid & 15;
                    const int g = (pp & 8) | ((pp & 7) ^ (row & 7));
                    gld_lds16(&vbase[(size_t)row * SEQ + k0 + g * 8],
                              &Vs[(i * 256 + w * 64) * 8]);
                }
            }
        }
        __syncthreads();   // RAW: compiler drains vmcnt before s_barrier

        const bool diag = (j == qt);

#pragma unroll
        for (int half = 0; half < 2; ++half) {
            // ---- S^T = K·Q^T (exp2 domain); exp; truncate-pack; b64 store ----
#pragma unroll
            for (int mt = 0; mt < 4; ++mt) {
                const int krow = half * 64 + mt * 16 + l15;
                s8v ka0 = *(const s8v*)&Kb[(krow * 8 + (quad ^ (l15 & 7))) * 8];
                s8v ka1 = *(const s8v*)&Kb[(krow * 8 + ((4 + quad) ^ (l15 & 7))) * 8];
#pragma unroll
                for (int ns = 0; ns < 2; ++ns) {
                    f4v st = (f4v){0.f, 0.f, 0.f, 0.f};
                    st = __builtin_amdgcn_mfma_f32_16x16x32_bf16(ka0, aq[ns][0], st, 0, 0, 0);
                    st = __builtin_amdgcn_mfma_f32_16x16x32_bf16(ka1, aq[ns][1], st, 0, 0, 0);
                    if (diag) {
#pragma unroll
                        for (int r = 0; r < 4; ++r)
                            if (half * 64 + mt * 16 + quad * 4 + r > qw + ns * 16 + l15)
                                st[r] = -INFINITY;
                    }
                    float e0 = exp2f(st[0]), e1 = exp2f(st[1]);
                    float e2 = exp2f(st[2]), e3 = exp2f(st[3]);
                    lsum[ns] += (e0 + e1) + (e2 + e3);
                    int2 pk;
                    pk.x = (int)((__float_as_uint(e0) >> 16) | (__float_as_uint(e1) & 0xffff0000u));
                    pk.y = (int)((__float_as_uint(e2) >> 16) | (__float_as_uint(e3) & 0xffff0000u));
                    *(int2*)&Ps[w][(ns * 16 + l15) * 72 + mt * 16 + quad * 4] = pk;
                }
            }
            // ---- O += P @ V (hoisted B-frags; Ps wave-private, in-order DS) ----
#pragma unroll
            for (int c2 = 0; c2 < 2; ++c2) {
                s8v ap0 = *(const s8v*)&Ps[w][l15 * 72 + c2 * 32 + quad * 8];
                s8v ap1 = *(const s8v*)&Ps[w][(16 + l15) * 72 + c2 * 32 + quad * 8];
                const int g = (half * 2 + c2) * 4 + quad;
                const int pos = (g & 8) | ((g & 7) ^ (l15 & 7));
                s8v bv[4];
#pragma unroll
                for (int nt = 0; nt < 4; ++nt)
                    bv[nt] = *(const s8v*)&Vs[((nt * 16 + l15) * 16 + pos) * 8];
#pragma unroll
                for (int nt = 0; nt < 4; ++nt) {
                    Oacc[0][nt] = __builtin_amdgcn_mfma_f32_16x16x32_bf16(
                        ap0, bv[nt], Oacc[0][nt], 0, 0, 0);
                    Oacc[1][nt] = __builtin_amdgcn_mfma_f32_16x16x32_bf16(
                        ap1, bv[nt], Oacc[1][nt], 0, 0, 0);
                }
            }
        }
    }

    // ---- write UNNORMALIZED partials: l (fp32) + O (bf16) ----
#pragma unroll
    for (int ns = 0; ns < 2; ++ns) {
        lsum[ns] += __shfl_xor(lsum[ns], 16, 64);
        lsum[ns] += __shfl_xor(lsum[ns], 32, 64);
    }
    float* L = Lp + ((size_t)seg << 16) + (size_t)bh * SEQ;
    if (quad == 0) {
        L[q0 + qw + l15]      = lsum[0];
        L[q0 + qw + 16 + l15] = lsum[1];
    }
    short* Op = (seg ? Op1 : Op0) + (size_t)bh * SEQ * D_HEAD;
#pragma unroll
    for (int ms = 0; ms < 2; ++ms)
#pragma unroll
        for (int r = 0; r < 4; ++r) {
            const int nloc = q0 + qw + ms * 16 + quad * 4 + r;
            short* dst = Op + (size_t)nloc * D_HEAD + l15;
#pragma unroll
            for (int nt = 0; nt < 4; ++nt)
                dst[nt * 16] = to_bf(Oacc[ms][nt][r]);
        }
}

// ---------------------------------------------------------------------------
// combine: ctx[n, h*64+dh] = (O0+O1)/(l0+l1).  Opart layout [bh][s][dh].
// ---------------------------------------------------------------------------
__global__ __launch_bounds__(256) void combine(
    const short* __restrict__ Op0, const short* __restrict__ Op1,
    const float* __restrict__ Lp, short* __restrict__ ctxb)
{
    const int id  = blockIdx.x * 256 + threadIdx.x;   // 524288 threads x 8 elems
    const int e   = id * 8;
    const int bh  = e >> 17;                          // / (SEQ*D_HEAD)
    const int rem = e & 131071;
    const int s   = rem >> 6, dh = rem & 63;
    const int b   = bh >> 4,  h  = bh & 15;

    int4 p0 = *(const int4*)&Op0[e];
    int4 p1 = *(const int4*)&Op1[e];
    const float inv = 1.f / (Lp[(size_t)bh * SEQ + s] + Lp[65536 + (size_t)bh * SEQ + s]);

    const unsigned* u0 = (const unsigned*)&p0;
    const unsigned* u1 = (const unsigned*)&p1;
    short outv[8];
#pragma unroll
    for (int i = 0; i < 4; ++i) {
        float a0 = __uint_as_float(u0[i] << 16), b0 = __uint_as_float(u0[i] & 0xffff0000u);
        float a1 = __uint_as_float(u1[i] << 16), b1 = __uint_as_float(u1[i] & 0xffff0000u);
        outv[2 * i]     = to_bf((a0 + a1) * inv);
        outv[2 * i + 1] = to_bf((b0 + b1) * inv);
    }
    short* dst = &ctxb[(size_t)(b * SEQ + s) * D_MODEL + h * D_HEAD + dh];
    *(int4*)dst = *(const int4*)outv;
}

// ---------------------------------------------------------------------------
extern "C" void kernel_launch(void* const* d_in, const int* in_sizes, int n_in,
                              void* d_out, int out_size, void* d_ws, size_t ws_size,
                              hipStream_t stream)
{
    const float* x  = (const float*)d_in[0];
    const float* Wq = (const float*)d_in[1];
    const float* bq = (const float*)d_in[2];
    const float* Wk = (const float*)d_in[3];
    const float* bk = (const float*)d_in[4];
    const float* Wv = (const float*)d_in[5];
    const float* bv = (const float*)d_in[6];
    const float* Wo = (const float*)d_in[7];
    const float* bo = (const float*)d_in[8];
    float* out = (float*)d_out;

    short* wsp = (short*)d_ws;
    const size_t MAT = (size_t)NROWS * D_MODEL;   // 4 Mi elements
    short* Qb    = wsp;                           // [ 0, 8) MB  bf16 Q (exp2 scale)
    short* Kbg   = Qb + MAT;                      // [ 8,16) MB  bf16 K
    short* Vtb   = Kbg + MAT;                     // [16,24) MB  bf16 V^T
    short* ctxb  = Vtb + MAT;                     // [24,32) MB  bf16 ctx
    short* Xb    = ctxb + MAT;                    // [32,40) MB  bf16 x (dead after QKV)
    short* Wqkvb = Xb + MAT;                      // [40,46) MB
    short* Wob   = Wqkvb + 3 * D_MODEL * D_MODEL; // [46,48) MB
    short* Op0   = Xb;                            // seg0 partial O aliases Xb
    short* Op1   = Wob + D_MODEL * D_MODEL;       // [48,56) MB
    float* Lp    = (float*)(Op1 + MAT);           // [56,56.5) MB: 2 x 64K floats

    cvt_fused<<<8192, 256, 0, stream>>>(x, Wq, Wk, Wv, Wo, Xb, Wqkvb, Wob);

    gemm_bf16<<<dim3(3 * D_MODEL / 128, NROWS / 128), 256, 0, stream>>>(
        Xb, Wqkvb, bq, bk, bv, nullptr, Qb, Kbg, Vtb, 1);

    attn_mfma<<<dim3(1024), 256, 0, stream>>>(Qb, Kbg, Vtb, Op0, Op1, Lp);

    combine<<<dim3(2048), 256, 0, stream>>>(Op0, Op1, Lp, ctxb);

    gemm_bf16<<<dim3(D_MODEL / 128, NROWS / 128), 256, 0, stream>>>(
        ctxb, Wob, bo, bo, bo, out, nullptr, nullptr, nullptr, 0);
}

// Round 8
// 213.810 us; speedup vs baseline: 12.3236x; 1.0080x over previous
//
#include <hip/hip_runtime.h>
#include <math.h>

#define D_MODEL 1024
#define NUM_HEADS 16
#define D_HEAD 64
#define SEQ 2048
#define BATCH 2
#define NROWS (BATCH * SEQ) /* 4096 */

typedef short s8v __attribute__((ext_vector_type(8)));   // 8 bf16 (4 VGPRs)
typedef float f4v __attribute__((ext_vector_type(4)));   // MFMA C/D

__device__ __forceinline__ short to_bf(float f) {
    union { float f; unsigned u; } x; x.f = f;
    unsigned r = x.u + 0x7fffu + ((x.u >> 16) & 1u);   // RNE
    return (short)(r >> 16);
}

// async global->LDS, 16 B/lane; LDS dest is wave-uniform base + lane*16
__device__ __forceinline__ void gld_lds16(const short* g, short* l) {
    __builtin_amdgcn_global_load_lds(
        (const __attribute__((address_space(1))) unsigned*)g,
        (__attribute__((address_space(3))) unsigned*)l, 16, 0, 0);
}

// Q pre-scale: 1/sqrt(Dh) * log2(e)  -> S leaves MFMA in exp2 domain
#define QSCALE 0.180336880f

// ---------------------------------------------------------------------------
// fp32 -> bf16 convert. Wq segment pre-scaled by QSCALE.
// ---------------------------------------------------------------------------
__global__ __launch_bounds__(256) void cvt_fused(
    const float* __restrict__ x,  const float* __restrict__ Wq,
    const float* __restrict__ Wk, const float* __restrict__ Wv,
    const float* __restrict__ Wo,
    short* __restrict__ Xb, short* __restrict__ Wqkvb, short* __restrict__ Wob)
{
    const int NX = NROWS * D_MODEL / 4;
    const int NW = D_MODEL * D_MODEL / 4;
    int j = blockIdx.x * 256 + threadIdx.x;
    const float* src; short* dst; float sc = 1.f;
    if (j < NX)                 { src = x;  dst = Xb; }
    else if ((j -= NX) < NW)    { src = Wq; dst = Wqkvb; sc = QSCALE; }
    else if ((j -= NW) < NW)    { src = Wk; dst = Wqkvb + NW * 4; }
    else if ((j -= NW) < NW)    { src = Wv; dst = Wqkvb + NW * 8; }
    else                        { j -= NW; src = Wo; dst = Wob; }
    float4 v = ((const float4*)src)[j];
    short4 s = { to_bf(v.x * sc), to_bf(v.y * sc), to_bf(v.z * sc), to_bf(v.w * sc) };
    ((short4*)dst)[j] = s;
}

// ---------------------------------------------------------------------------
// QKV bf16 MFMA GEMM: 128x128, BK=64, 4 waves, XOR-swizzled LDS chunks.
// 1-D grid of 768 blocks, XCD-locality mapping: xcd = bx&7 owns a 12n x 8m
// region -> per-XCD working set ~5 MB (W 3 + X 2) vs 14 MB unswizzled.
// Epilogue: bf16 Q [B,H,S,Dh], K [B,H,S,Dh], V^T [B,H,Dh,S] via LDS repack.
// ---------------------------------------------------------------------------
__global__ __launch_bounds__(256) void gemm_qkv(
    const short* __restrict__ Xb, const short* __restrict__ Wb,
    const float* __restrict__ B0, const float* __restrict__ B1, const float* __restrict__ B2,
    short* __restrict__ Q0, short* __restrict__ K1, short* __restrict__ V2)
{
    __shared__ __align__(16) short smem[18432];
    short* As = smem;
    short* Bs = smem + 8192;

    const int t    = threadIdx.x;
    const int w    = t >> 6;
    const int lane = t & 63;
    const int quad = lane >> 4;
    const int l15  = lane & 15;
    const int wm   = w & 1, wn = w >> 1;

    // XCD-locality swizzle: region (n_half, m_q) per XCD; 12n x 8m inside.
    const int bx    = blockIdx.x;
    const int xcd   = bx & 7;
    const int g_    = bx >> 3;            // 0..95
    const int n_loc = g_ % 12;
    const int m_loc = g_ / 12;            // 0..7
    const int n0 = ((xcd >> 2) * 12 + n_loc) * 128;
    const int m0 = ((xcd & 3) * 8 + m_loc) * 128;

    f4v acc[4][4];
#pragma unroll
    for (int i = 0; i < 4; ++i)
#pragma unroll
        for (int j = 0; j < 4; ++j) acc[i][j] = (f4v){0.f, 0.f, 0.f, 0.f};

    for (int k0 = 0; k0 < D_MODEL; k0 += 64) {
#pragma unroll
        for (int i = 0; i < 4; ++i) {
            const int cid = i * 256 + t;
            const int row = cid >> 3, kc = cid & 7, g = kc ^ (row & 7);
            gld_lds16(&Xb[(size_t)(m0 + row) * D_MODEL + k0 + g * 8],
                      &As[(i * 256 + w * 64) * 8]);
            gld_lds16(&Wb[(size_t)(n0 + row) * D_MODEL + k0 + g * 8],
                      &Bs[(i * 256 + w * 64) * 8]);
        }
        __syncthreads();

#pragma unroll
        for (int c = 0; c < 2; ++c) {
            s8v af[4], bf[4];
            const int pos = ((c * 4 + quad) ^ (l15 & 7)) * 8;
#pragma unroll
            for (int mi = 0; mi < 4; ++mi)
                af[mi] = *(const s8v*)&As[(wm * 64 + mi * 16 + l15) * 64 + pos];
#pragma unroll
            for (int ni = 0; ni < 4; ++ni)
                bf[ni] = *(const s8v*)&Bs[(wn * 64 + ni * 16 + l15) * 64 + pos];
#pragma unroll
            for (int mi = 0; mi < 4; ++mi)
#pragma unroll
                for (int ni = 0; ni < 4; ++ni)
                    acc[mi][ni] = __builtin_amdgcn_mfma_f32_16x16x32_bf16(
                        af[mi], bf[ni], acc[mi][ni], 0, 0, 0);
        }
        __syncthreads();
    }

    const int sel = n0 >> 10;
    const float* bias = sel == 0 ? B0 : sel == 1 ? B1 : B2;
    short* out        = sel == 0 ? Q0 : sel == 1 ? K1 : V2;
    const float bsc   = sel == 0 ? QSCALE : 1.f;
    const int h0 = (n0 & 1023) >> 6;

#pragma unroll
    for (int ni = 0; ni < 4; ++ni) {
        const int col = wn * 64 + ni * 16 + l15;
        const float bv = bias[(n0 & 1023) + col] * bsc;
#pragma unroll
        for (int mi = 0; mi < 4; ++mi)
#pragma unroll
            for (int r = 0; r < 4; ++r) {
                const int row = wm * 64 + mi * 16 + quad * 4 + r;
                const short v = to_bf(acc[mi][ni][r] + bv);
                if (sel < 2) smem[row * 144 + col] = v;
                else         smem[col * 144 + row] = v;
            }
    }
    __syncthreads();

    const int rr = t >> 1, half = t & 1;
    const int bb = m0 >> 11, mloc = m0 & (SEQ - 1);
    const short* src = &smem[rr * 144 + half * 64];
    short* dst;
    if (sel < 2)
        dst = out + (((size_t)(bb * NUM_HEADS + h0 + half) * SEQ + (mloc + rr)) * D_HEAD);
    else
        dst = out + ((size_t)(bb * NUM_HEADS + h0 + (rr >> 6)) * D_HEAD + (rr & 63)) * SEQ
                  + mloc + half * 64;
#pragma unroll
    for (int i = 0; i < 8; ++i)
        ((int4*)dst)[i] = ((const int4*)src)[i];
}

// ---------------------------------------------------------------------------
// MFMA flash attention v5 (unchanged from R7): key-split flash-decoding,
// 1024 blocks, fixed-shift additive partials -> Op0/Op1 (bf16) + Lp (fp32).
// ---------------------------------------------------------------------------
__global__ __launch_bounds__(256) void attn_mfma(
    const short* __restrict__ Qg, const short* __restrict__ Kg,
    const short* __restrict__ Vg,
    short* __restrict__ Op0, short* __restrict__ Op1, float* __restrict__ Lp)
{
    __shared__ __align__(16) short Kb[128 * 64];     // 16 KB  [key][d]
    __shared__ __align__(16) short Vs[64 * 128];     // 16 KB  [d][key]
    __shared__ __align__(16) short Ps[4][32 * 72];   // 18 KB  per-wave [q][key64]

    const int t    = threadIdx.x;
    const int w    = t >> 6;
    const int lane = t & 63;
    const int quad = lane >> 4;
    const int l15  = lane & 15;

    const int bidx = blockIdx.x;
    const int seg  = bidx >> 9;               // key parity
    const int p    = bidx & 255;
    const int bh   = p >> 3;
    const int pair = p & 7;
    const int qt   = ((bidx >> 8) & 1) ? 15 - pair : pair;
    const int b    = bh >> 4, h = bh & 15;
    (void)b; (void)h;

    const short* qbase = Qg + (size_t)bh * SEQ * D_HEAD;
    const short* kbase = Kg + (size_t)bh * SEQ * D_HEAD;
    const short* vbase = Vg + (size_t)bh * D_HEAD * SEQ;
    const int q0 = qt * 128;
    const int qw = w * 32;

    s8v aq[2][2];
#pragma unroll
    for (int ns = 0; ns < 2; ++ns)
#pragma unroll
        for (int c = 0; c < 2; ++c)
            aq[ns][c] = *(const s8v*)&qbase[(size_t)(q0 + qw + ns * 16 + l15) * D_HEAD
                                            + c * 32 + quad * 8];

    f4v Oacc[2][4];
#pragma unroll
    for (int ms = 0; ms < 2; ++ms)
#pragma unroll
        for (int nt = 0; nt < 4; ++nt) Oacc[ms][nt] = (f4v){0.f, 0.f, 0.f, 0.f};
    float lsum[2] = {0.f, 0.f};

    for (int j = seg; j <= qt; j += 2) {
        __syncthreads();
        {
            const int k0 = j * 128;
#pragma unroll
            for (int i = 0; i < 4; ++i) {
                const int cid = i * 256 + w * 64 + lane;
                {
                    const int row = cid >> 3, pp = cid & 7, g = pp ^ (row & 7);
                    gld_lds16(&kbase[(size_t)(k0 + row) * D_HEAD + g * 8],
                              &Kb[(i * 256 + w * 64) * 8]);
                }
                {
                    const int row = cid >> 4, pp = cid & 15;
                    const int g = (pp & 8) | ((pp & 7) ^ (row & 7));
                    gld_lds16(&vbase[(size_t)row * SEQ + k0 + g * 8],
                              &Vs[(i * 256 + w * 64) * 8]);
                }
            }
        }
        __syncthreads();

        const bool diag = (j == qt);

#pragma unroll
        for (int half = 0; half < 2; ++half) {
#pragma unroll
            for (int mt = 0; mt < 4; ++mt) {
                const int krow = half * 64 + mt * 16 + l15;
                s8v ka0 = *(const s8v*)&Kb[(krow * 8 + (quad ^ (l15 & 7))) * 8];
                s8v ka1 = *(const s8v*)&Kb[(krow * 8 + ((4 + quad) ^ (l15 & 7))) * 8];
#pragma unroll
                for (int ns = 0; ns < 2; ++ns) {
                    f4v st = (f4v){0.f, 0.f, 0.f, 0.f};
                    st = __builtin_amdgcn_mfma_f32_16x16x32_bf16(ka0, aq[ns][0], st, 0, 0, 0);
                    st = __builtin_amdgcn_mfma_f32_16x16x32_bf16(ka1, aq[ns][1], st, 0, 0, 0);
                    if (diag) {
#pragma unroll
                        for (int r = 0; r < 4; ++r)
                            if (half * 64 + mt * 16 + quad * 4 + r > qw + ns * 16 + l15)
                                st[r] = -INFINITY;
                    }
                    float e0 = exp2f(st[0]), e1 = exp2f(st[1]);
                    float e2 = exp2f(st[2]), e3 = exp2f(st[3]);
                    lsum[ns] += (e0 + e1) + (e2 + e3);
                    int2 pk;
                    pk.x = (int)((__float_as_uint(e0) >> 16) | (__float_as_uint(e1) & 0xffff0000u));
                    pk.y = (int)((__float_as_uint(e2) >> 16) | (__float_as_uint(e3) & 0xffff0000u));
                    *(int2*)&Ps[w][(ns * 16 + l15) * 72 + mt * 16 + quad * 4] = pk;
                }
            }
#pragma unroll
            for (int c2 = 0; c2 < 2; ++c2) {
                s8v ap0 = *(const s8v*)&Ps[w][l15 * 72 + c2 * 32 + quad * 8];
                s8v ap1 = *(const s8v*)&Ps[w][(16 + l15) * 72 + c2 * 32 + quad * 8];
                const int g = (half * 2 + c2) * 4 + quad;
                const int pos = (g & 8) | ((g & 7) ^ (l15 & 7));
                s8v bv[4];
#pragma unroll
                for (int nt = 0; nt < 4; ++nt)
                    bv[nt] = *(const s8v*)&Vs[((nt * 16 + l15) * 16 + pos) * 8];
#pragma unroll
                for (int nt = 0; nt < 4; ++nt) {
                    Oacc[0][nt] = __builtin_amdgcn_mfma_f32_16x16x32_bf16(
                        ap0, bv[nt], Oacc[0][nt], 0, 0, 0);
                    Oacc[1][nt] = __builtin_amdgcn_mfma_f32_16x16x32_bf16(
                        ap1, bv[nt], Oacc[1][nt], 0, 0, 0);
                }
            }
        }
    }

#pragma unroll
    for (int ns = 0; ns < 2; ++ns) {
        lsum[ns] += __shfl_xor(lsum[ns], 16, 64);
        lsum[ns] += __shfl_xor(lsum[ns], 32, 64);
    }
    float* L = Lp + ((size_t)seg << 16) + (size_t)bh * SEQ;
    if (quad == 0) {
        L[q0 + qw + l15]      = lsum[0];
        L[q0 + qw + 16 + l15] = lsum[1];
    }
    short* Op = (seg ? Op1 : Op0) + (size_t)bh * SEQ * D_HEAD;
#pragma unroll
    for (int ms = 0; ms < 2; ++ms)
#pragma unroll
        for (int r = 0; r < 4; ++r) {
            const int nloc = q0 + qw + ms * 16 + quad * 4 + r;
            short* dst = Op + (size_t)nloc * D_HEAD + l15;
#pragma unroll
            for (int nt = 0; nt < 4; ++nt)
                dst[nt * 16] = to_bf(Oacc[ms][nt][r]);
        }
}

// ---------------------------------------------------------------------------
// O-projection with FUSED combine: out = ((O0+O1)*inv) @ Wo^T + bo.
// 128M x 64N tiles, BK=64 -> one head per K-step (h = k0>>6); grid 512.
// A-tile built by VALU from Op0/Op1 partials (bf16) * inv[h][s] (LDS table);
// B-tile staged by global_load_lds. XOR chunk swizzle throughout.
// ---------------------------------------------------------------------------
__global__ __launch_bounds__(256) void gemm_oproj(
    const short* __restrict__ Op0, const short* __restrict__ Op1,
    const float* __restrict__ Lp, const short* __restrict__ Wob,
    const float* __restrict__ bo, float* __restrict__ out)
{
    __shared__ __align__(16) short As[128 * 64];   // 16 KB
    __shared__ __align__(16) short Bs[64 * 64];    //  8 KB
    __shared__ float invL[NUM_HEADS * 128];        //  8 KB: inv[h][row]

    const int t    = threadIdx.x;
    const int w    = t >> 6;
    const int lane = t & 63;
    const int quad = lane >> 4;
    const int l15  = lane & 15;
    const int wm   = w & 1, wn = w >> 1;

    const int n0 = blockIdx.x * 64;
    const int m0 = blockIdx.y * 128;
    const int bb = m0 >> 11, sloc = m0 & (SEQ - 1);

    // inv table: 16 heads x 128 rows, once per block
#pragma unroll
    for (int ii = 0; ii < 8; ++ii) {
        const int idx = t * 8 + ii;
        const int hh = idx >> 7, sl = idx & 127;
        const size_t loff = (size_t)(bb * NUM_HEADS + hh) * SEQ + sloc + sl;
        invL[idx] = 1.f / (Lp[loff] + Lp[65536 + loff]);
    }
    __syncthreads();

    f4v acc[4][2];
#pragma unroll
    for (int i = 0; i < 4; ++i)
#pragma unroll
        for (int j = 0; j < 2; ++j) acc[i][j] = (f4v){0.f, 0.f, 0.f, 0.f};

    for (int k0 = 0; k0 < D_MODEL; k0 += 64) {
        const int h = k0 >> 6;
        // B tile first (DMA overlaps A's VALU work)
#pragma unroll
        for (int i = 0; i < 2; ++i) {
            const int cid = i * 256 + w * 64 + lane;
            const int row = cid >> 3, pp = cid & 7, g = pp ^ (row & 7);
            gld_lds16(&Wob[(size_t)(n0 + row) * D_MODEL + k0 + g * 8],
                      &Bs[(i * 256 + w * 64) * 8]);
        }
        // A tile: combine partials, scale, pack bf16, ds_write
        const size_t obase = ((size_t)(bb * NUM_HEADS + h) * SEQ + sloc) * D_HEAD;
#pragma unroll
        for (int i = 0; i < 4; ++i) {
            const int cid = i * 256 + t;
            const int row = cid >> 3, pp = cid & 7, g = pp ^ (row & 7);
            const size_t off = obase + (size_t)row * D_HEAD + g * 8;
            int4 a0 = *(const int4*)&Op0[off];
            int4 a1 = *(const int4*)&Op1[off];
            const float inv = invL[h * 128 + row];
            const unsigned* u0 = (const unsigned*)&a0;
            const unsigned* u1 = (const unsigned*)&a1;
            int4 o;
#pragma unroll
            for (int d = 0; d < 4; ++d) {
                float lo = (__uint_as_float(u0[d] << 16) +
                            __uint_as_float(u1[d] << 16)) * inv;
                float hi = (__uint_as_float(u0[d] & 0xffff0000u) +
                            __uint_as_float(u1[d] & 0xffff0000u)) * inv;
                ((unsigned*)&o)[d] = (__float_as_uint(lo) >> 16) |
                                     (__float_as_uint(hi) & 0xffff0000u);
            }
            *(int4*)&As[cid * 8] = o;
        }
        __syncthreads();

#pragma unroll
        for (int c = 0; c < 2; ++c) {
            s8v af[4], bf[2];
            const int pos = ((c * 4 + quad) ^ (l15 & 7)) * 8;
#pragma unroll
            for (int mi = 0; mi < 4; ++mi)
                af[mi] = *(const s8v*)&As[(wm * 64 + mi * 16 + l15) * 64 + pos];
#pragma unroll
            for (int ni = 0; ni < 2; ++ni)
                bf[ni] = *(const s8v*)&Bs[(wn * 32 + ni * 16 + l15) * 64 + pos];
#pragma unroll
            for (int mi = 0; mi < 4; ++mi)
#pragma unroll
                for (int ni = 0; ni < 2; ++ni)
                    acc[mi][ni] = __builtin_amdgcn_mfma_f32_16x16x32_bf16(
                        af[mi], bf[ni], acc[mi][ni], 0, 0, 0);
        }
        __syncthreads();
    }

#pragma unroll
    for (int ni = 0; ni < 2; ++ni) {
        const int col = n0 + wn * 32 + ni * 16 + l15;
        const float bv = bo[col];
#pragma unroll
        for (int mi = 0; mi < 4; ++mi)
#pragma unroll
            for (int r = 0; r < 4; ++r) {
                const int row = m0 + wm * 64 + mi * 16 + quad * 4 + r;
                out[(size_t)row * D_MODEL + col] = acc[mi][ni][r] + bv;
            }
    }
}

// ---------------------------------------------------------------------------
extern "C" void kernel_launch(void* const* d_in, const int* in_sizes, int n_in,
                              void* d_out, int out_size, void* d_ws, size_t ws_size,
                              hipStream_t stream)
{
    const float* x  = (const float*)d_in[0];
    const float* Wq = (const float*)d_in[1];
    const float* bq = (const float*)d_in[2];
    const float* Wk = (const float*)d_in[3];
    const float* bk = (const float*)d_in[4];
    const float* Wv = (const float*)d_in[5];
    const float* bv = (const float*)d_in[6];
    const float* Wo = (const float*)d_in[7];
    const float* bo = (const float*)d_in[8];
    float* out = (float*)d_out;

    short* wsp = (short*)d_ws;
    const size_t MAT = (size_t)NROWS * D_MODEL;   // 4 Mi elements
    short* Qb    = wsp;                           // [ 0, 8) MB  bf16 Q (exp2 scale)
    short* Kbg   = Qb + MAT;                      // [ 8,16) MB  bf16 K
    short* Vtb   = Kbg + MAT;                     // [16,24) MB  bf16 V^T
    short* Xb    = Vtb + 2 * MAT;                 // [32,40) MB  bf16 x (dead after QKV)
    short* Wqkvb = Xb + MAT;                      // [40,46) MB
    short* Wob   = Wqkvb + 3 * D_MODEL * D_MODEL; // [46,48) MB
    short* Op0   = Xb;                            // seg0 partial O aliases Xb
    short* Op1   = Wob + D_MODEL * D_MODEL;       // [48,56) MB
    float* Lp    = (float*)(Op1 + MAT);           // [56,56.5) MB: 2 x 64K floats

    cvt_fused<<<8192, 256, 0, stream>>>(x, Wq, Wk, Wv, Wo, Xb, Wqkvb, Wob);

    gemm_qkv<<<768, 256, 0, stream>>>(Xb, Wqkvb, bq, bk, bv, Qb, Kbg, Vtb);

    attn_mfma<<<1024, 256, 0, stream>>>(Qb, Kbg, Vtb, Op0, Op1, Lp);

    gemm_oproj<<<dim3(D_MODEL / 64, NROWS / 128), 256, 0, stream>>>(
        Op0, Op1, Lp, Wob, bo, out);
}

// Round 9
// 206.307 us; speedup vs baseline: 12.7717x; 1.0364x over previous
//
#include <hip/hip_runtime.h>
#include <math.h>

#define D_MODEL 1024
#define NUM_HEADS 16
#define D_HEAD 64
#define SEQ 2048
#define BATCH 2
#define NROWS (BATCH * SEQ) /* 4096 */

typedef short s8v __attribute__((ext_vector_type(8)));   // 8 bf16 (4 VGPRs)
typedef float f4v __attribute__((ext_vector_type(4)));   // MFMA C/D

__device__ __forceinline__ short to_bf(float f) {
    union { float f; unsigned u; } x; x.f = f;
    unsigned r = x.u + 0x7fffu + ((x.u >> 16) & 1u);   // RNE
    return (short)(r >> 16);
}

__device__ __forceinline__ unsigned pack_bf2(float a, float b) {
    return (unsigned)(unsigned short)to_bf(a) | ((unsigned)(unsigned short)to_bf(b) << 16);
}

// async global->LDS, 16 B/lane; LDS dest is wave-uniform base + lane*16
__device__ __forceinline__ void gld_lds16(const short* g, short* l) {
    __builtin_amdgcn_global_load_lds(
        (const __attribute__((address_space(1))) unsigned*)g,
        (__attribute__((address_space(3))) unsigned*)l, 16, 0, 0);
}

// Q pre-scale: 1/sqrt(Dh) * log2(e)  -> S leaves MFMA in exp2 domain
#define QSCALE 0.180336880f

// ---------------------------------------------------------------------------
// fp32 -> bf16 convert. Wq segment pre-scaled by QSCALE.
// ---------------------------------------------------------------------------
__global__ __launch_bounds__(256) void cvt_fused(
    const float* __restrict__ x,  const float* __restrict__ Wq,
    const float* __restrict__ Wk, const float* __restrict__ Wv,
    const float* __restrict__ Wo,
    short* __restrict__ Xb, short* __restrict__ Wqkvb, short* __restrict__ Wob)
{
    const int NX = NROWS * D_MODEL / 4;
    const int NW = D_MODEL * D_MODEL / 4;
    int j = blockIdx.x * 256 + threadIdx.x;
    const float* src; short* dst; float sc = 1.f;
    if (j < NX)                 { src = x;  dst = Xb; }
    else if ((j -= NX) < NW)    { src = Wq; dst = Wqkvb; sc = QSCALE; }
    else if ((j -= NW) < NW)    { src = Wk; dst = Wqkvb + NW * 4; }
    else if ((j -= NW) < NW)    { src = Wv; dst = Wqkvb + NW * 8; }
    else                        { j -= NW; src = Wo; dst = Wob; }
    float4 v = ((const float4*)src)[j];
    short4 s = { to_bf(v.x * sc), to_bf(v.y * sc), to_bf(v.z * sc), to_bf(v.w * sc) };
    ((short4*)dst)[j] = s;
}

// ---------------------------------------------------------------------------
// QKV bf16 MFMA GEMM: 128x128, BK=64, 4 waves, XOR-swizzled LDS chunks,
// XCD-locality grid mapping (768 blocks).
// Q/K blocks (n0 < 2048): TRANSPOSED accumulate C^T = mfma(W_frag, X_frag)
//   -> lane regs = 4 consecutive dh -> direct 8-B stores into [B,H,S,Dh].
// V blocks: normal accumulate -> lane regs = 4 consecutive s -> direct 8-B
//   stores into V^T [B,H,Dh,S].  No epilogue LDS repack at all.
// ---------------------------------------------------------------------------
__global__ __launch_bounds__(256) void gemm_qkv(
    const short* __restrict__ Xb, const short* __restrict__ Wb,
    const float* __restrict__ B0, const float* __restrict__ B1, const float* __restrict__ B2,
    short* __restrict__ Q0, short* __restrict__ K1, short* __restrict__ V2)
{
    __shared__ __align__(16) short As[128 * 64];   // 16 KB
    __shared__ __align__(16) short Bs[128 * 64];   // 16 KB

    const int t    = threadIdx.x;
    const int w    = t >> 6;
    const int lane = t & 63;
    const int quad = lane >> 4;
    const int l15  = lane & 15;
    const int wm   = w & 1, wn = w >> 1;

    // XCD-locality swizzle: region (n_half, m_q) per XCD; 12n x 8m inside.
    const int bx    = blockIdx.x;
    const int xcd   = bx & 7;
    const int g_    = bx >> 3;            // 0..95
    const int n_loc = g_ % 12;
    const int m_loc = g_ / 12;            // 0..7
    const int n0 = ((xcd >> 2) * 12 + n_loc) * 128;
    const int m0 = ((xcd & 3) * 8 + m_loc) * 128;

    const bool swapT = (n0 < 2048);       // Q/K -> transposed accumulate

    f4v acc[4][4];
#pragma unroll
    for (int i = 0; i < 4; ++i)
#pragma unroll
        for (int j = 0; j < 4; ++j) acc[i][j] = (f4v){0.f, 0.f, 0.f, 0.f};

    for (int k0 = 0; k0 < D_MODEL; k0 += 64) {
#pragma unroll
        for (int i = 0; i < 4; ++i) {
            const int cid = i * 256 + t;
            const int row = cid >> 3, kc = cid & 7, g = kc ^ (row & 7);
            gld_lds16(&Xb[(size_t)(m0 + row) * D_MODEL + k0 + g * 8],
                      &As[(i * 256 + w * 64) * 8]);
            gld_lds16(&Wb[(size_t)(n0 + row) * D_MODEL + k0 + g * 8],
                      &Bs[(i * 256 + w * 64) * 8]);
        }
        __syncthreads();

#pragma unroll
        for (int c = 0; c < 2; ++c) {
            s8v af[4], bf[4];
            const int pos = ((c * 4 + quad) ^ (l15 & 7)) * 8;
#pragma unroll
            for (int mi = 0; mi < 4; ++mi)
                af[mi] = *(const s8v*)&As[(wm * 64 + mi * 16 + l15) * 64 + pos];
#pragma unroll
            for (int ni = 0; ni < 4; ++ni)
                bf[ni] = *(const s8v*)&Bs[(wn * 64 + ni * 16 + l15) * 64 + pos];
            if (swapT) {
#pragma unroll
                for (int mi = 0; mi < 4; ++mi)
#pragma unroll
                    for (int ni = 0; ni < 4; ++ni)
                        acc[mi][ni] = __builtin_amdgcn_mfma_f32_16x16x32_bf16(
                            bf[ni], af[mi], acc[mi][ni], 0, 0, 0);
            } else {
#pragma unroll
                for (int mi = 0; mi < 4; ++mi)
#pragma unroll
                    for (int ni = 0; ni < 4; ++ni)
                        acc[mi][ni] = __builtin_amdgcn_mfma_f32_16x16x32_bf16(
                            af[mi], bf[ni], acc[mi][ni], 0, 0, 0);
            }
        }
        __syncthreads();
    }

    if (swapT) {
        // ---- Q/K: lane = s row (l15), regs = 4 consecutive dh (quad*4+r) ----
        const int sel = n0 >> 10;                   // 0 or 1
        const float* bias = sel == 0 ? B0 : B1;
        short* out        = sel == 0 ? Q0 : K1;
        const float bsc   = sel == 0 ? QSCALE : 1.f;
        const int nb = n0 & 1023;
#pragma unroll
        for (int ni = 0; ni < 4; ++ni) {
            const int colb = nb + wn * 64 + ni * 16 + quad * 4;   // 4-aligned
            float4 bv = *(const float4*)&bias[colb];
            const int h = colb >> 6, dh = colb & 63;
#pragma unroll
            for (int mi = 0; mi < 4; ++mi) {
                const int row = m0 + wm * 64 + mi * 16 + l15;
                const int bb = row >> 11, sl = row & (SEQ - 1);
                int2 pk;
                pk.x = (int)pack_bf2(acc[mi][ni][0] + bv.x * bsc,
                                     acc[mi][ni][1] + bv.y * bsc);
                pk.y = (int)pack_bf2(acc[mi][ni][2] + bv.z * bsc,
                                     acc[mi][ni][3] + bv.w * bsc);
                *(int2*)&out[(((size_t)(bb * NUM_HEADS + h) * SEQ) + sl) * D_HEAD + dh] = pk;
            }
        }
    } else {
        // ---- V: lane = dh col (l15), regs = 4 consecutive s (quad*4+r) ----
        const int nb = n0 & 1023;
#pragma unroll
        for (int ni = 0; ni < 4; ++ni) {
            const int col = nb + wn * 64 + ni * 16 + l15;
            const int h = col >> 6, dh = col & 63;
            const float bv = B2[col];
#pragma unroll
            for (int mi = 0; mi < 4; ++mi) {
                const int row = m0 + wm * 64 + mi * 16 + quad * 4;
                const int bb = row >> 11, sl = row & (SEQ - 1);
                int2 pk;
                pk.x = (int)pack_bf2(acc[mi][ni][0] + bv, acc[mi][ni][1] + bv);
                pk.y = (int)pack_bf2(acc[mi][ni][2] + bv, acc[mi][ni][3] + bv);
                *(int2*)&V2[((size_t)(bb * NUM_HEADS + h) * D_HEAD + dh) * SEQ + sl] = pk;
            }
        }
    }
}

// ---------------------------------------------------------------------------
// MFMA flash attention v5 (unchanged): key-split flash-decoding, 1024 blocks,
// fixed-shift additive partials -> Op0/Op1 (bf16) + Lp (fp32).
// ---------------------------------------------------------------------------
__global__ __launch_bounds__(256) void attn_mfma(
    const short* __restrict__ Qg, const short* __restrict__ Kg,
    const short* __restrict__ Vg,
    short* __restrict__ Op0, short* __restrict__ Op1, float* __restrict__ Lp)
{
    __shared__ __align__(16) short Kb[128 * 64];     // 16 KB  [key][d]
    __shared__ __align__(16) short Vs[64 * 128];     // 16 KB  [d][key]
    __shared__ __align__(16) short Ps[4][32 * 72];   // 18 KB  per-wave [q][key64]

    const int t    = threadIdx.x;
    const int w    = t >> 6;
    const int lane = t & 63;
    const int quad = lane >> 4;
    const int l15  = lane & 15;

    const int bidx = blockIdx.x;
    const int seg  = bidx >> 9;               // key parity
    const int p    = bidx & 255;
    const int bh   = p >> 3;
    const int pair = p & 7;
    const int qt   = ((bidx >> 8) & 1) ? 15 - pair : pair;

    const short* qbase = Qg + (size_t)bh * SEQ * D_HEAD;
    const short* kbase = Kg + (size_t)bh * SEQ * D_HEAD;
    const short* vbase = Vg + (size_t)bh * D_HEAD * SEQ;
    const int q0 = qt * 128;
    const int qw = w * 32;

    s8v aq[2][2];
#pragma unroll
    for (int ns = 0; ns < 2; ++ns)
#pragma unroll
        for (int c = 0; c < 2; ++c)
            aq[ns][c] = *(const s8v*)&qbase[(size_t)(q0 + qw + ns * 16 + l15) * D_HEAD
                                            + c * 32 + quad * 8];

    f4v Oacc[2][4];
#pragma unroll
    for (int ms = 0; ms < 2; ++ms)
#pragma unroll
        for (int nt = 0; nt < 4; ++nt) Oacc[ms][nt] = (f4v){0.f, 0.f, 0.f, 0.f};
    float lsum[2] = {0.f, 0.f};

    for (int j = seg; j <= qt; j += 2) {
        __syncthreads();
        {
            const int k0 = j * 128;
#pragma unroll
            for (int i = 0; i < 4; ++i) {
                const int cid = i * 256 + w * 64 + lane;
                {
                    const int row = cid >> 3, pp = cid & 7, g = pp ^ (row & 7);
                    gld_lds16(&kbase[(size_t)(k0 + row) * D_HEAD + g * 8],
                              &Kb[(i * 256 + w * 64) * 8]);
                }
                {
                    const int row = cid >> 4, pp = cid & 15;
                    const int g = (pp & 8) | ((pp & 7) ^ (row & 7));
                    gld_lds16(&vbase[(size_t)row * SEQ + k0 + g * 8],
                              &Vs[(i * 256 + w * 64) * 8]);
                }
            }
        }
        __syncthreads();

        const bool diag = (j == qt);

#pragma unroll
        for (int half = 0; half < 2; ++half) {
#pragma unroll
            for (int mt = 0; mt < 4; ++mt) {
                const int krow = half * 64 + mt * 16 + l15;
                s8v ka0 = *(const s8v*)&Kb[(krow * 8 + (quad ^ (l15 & 7))) * 8];
                s8v ka1 = *(const s8v*)&Kb[(krow * 8 + ((4 + quad) ^ (l15 & 7))) * 8];
#pragma unroll
                for (int ns = 0; ns < 2; ++ns) {
                    f4v st = (f4v){0.f, 0.f, 0.f, 0.f};
                    st = __builtin_amdgcn_mfma_f32_16x16x32_bf16(ka0, aq[ns][0], st, 0, 0, 0);
                    st = __builtin_amdgcn_mfma_f32_16x16x32_bf16(ka1, aq[ns][1], st, 0, 0, 0);
                    if (diag) {
#pragma unroll
                        for (int r = 0; r < 4; ++r)
                            if (half * 64 + mt * 16 + quad * 4 + r > qw + ns * 16 + l15)
                                st[r] = -INFINITY;
                    }
                    float e0 = exp2f(st[0]), e1 = exp2f(st[1]);
                    float e2 = exp2f(st[2]), e3 = exp2f(st[3]);
                    lsum[ns] += (e0 + e1) + (e2 + e3);
                    int2 pk;
                    pk.x = (int)((__float_as_uint(e0) >> 16) | (__float_as_uint(e1) & 0xffff0000u));
                    pk.y = (int)((__float_as_uint(e2) >> 16) | (__float_as_uint(e3) & 0xffff0000u));
                    *(int2*)&Ps[w][(ns * 16 + l15) * 72 + mt * 16 + quad * 4] = pk;
                }
            }
#pragma unroll
            for (int c2 = 0; c2 < 2; ++c2) {
                s8v ap0 = *(const s8v*)&Ps[w][l15 * 72 + c2 * 32 + quad * 8];
                s8v ap1 = *(const s8v*)&Ps[w][(16 + l15) * 72 + c2 * 32 + quad * 8];
                const int g = (half * 2 + c2) * 4 + quad;
                const int pos = (g & 8) | ((g & 7) ^ (l15 & 7));
                s8v bv[4];
#pragma unroll
                for (int nt = 0; nt < 4; ++nt)
                    bv[nt] = *(const s8v*)&Vs[((nt * 16 + l15) * 16 + pos) * 8];
#pragma unroll
                for (int nt = 0; nt < 4; ++nt) {
                    Oacc[0][nt] = __builtin_amdgcn_mfma_f32_16x16x32_bf16(
                        ap0, bv[nt], Oacc[0][nt], 0, 0, 0);
                    Oacc[1][nt] = __builtin_amdgcn_mfma_f32_16x16x32_bf16(
                        ap1, bv[nt], Oacc[1][nt], 0, 0, 0);
                }
            }
        }
    }

#pragma unroll
    for (int ns = 0; ns < 2; ++ns) {
        lsum[ns] += __shfl_xor(lsum[ns], 16, 64);
        lsum[ns] += __shfl_xor(lsum[ns], 32, 64);
    }
    float* L = Lp + ((size_t)seg << 16) + (size_t)bh * SEQ;
    if (quad == 0) {
        L[q0 + qw + l15]      = lsum[0];
        L[q0 + qw + 16 + l15] = lsum[1];
    }
    short* Op = (seg ? Op1 : Op0) + (size_t)bh * SEQ * D_HEAD;
#pragma unroll
    for (int ms = 0; ms < 2; ++ms)
#pragma unroll
        for (int r = 0; r < 4; ++r) {
            const int nloc = q0 + qw + ms * 16 + quad * 4 + r;
            short* dst = Op + (size_t)nloc * D_HEAD + l15;
#pragma unroll
            for (int nt = 0; nt < 4; ++nt)
                dst[nt * 16] = to_bf(Oacc[ms][nt][r]);
        }
}

// ---------------------------------------------------------------------------
// O-projection with FUSED combine (unchanged from R8): 128M x 64N, grid 512.
// ---------------------------------------------------------------------------
__global__ __launch_bounds__(256) void gemm_oproj(
    const short* __restrict__ Op0, const short* __restrict__ Op1,
    const float* __restrict__ Lp, const short* __restrict__ Wob,
    const float* __restrict__ bo, float* __restrict__ out)
{
    __shared__ __align__(16) short As[128 * 64];   // 16 KB
    __shared__ __align__(16) short Bs[64 * 64];    //  8 KB
    __shared__ float invL[NUM_HEADS * 128];        //  8 KB: inv[h][row]

    const int t    = threadIdx.x;
    const int w    = t >> 6;
    const int lane = t & 63;
    const int quad = lane >> 4;
    const int l15  = lane & 15;
    const int wm   = w & 1, wn = w >> 1;

    const int n0 = blockIdx.x * 64;
    const int m0 = blockIdx.y * 128;
    const int bb = m0 >> 11, sloc = m0 & (SEQ - 1);

#pragma unroll
    for (int ii = 0; ii < 8; ++ii) {
        const int idx = t * 8 + ii;
        const int hh = idx >> 7, sl = idx & 127;
        const size_t loff = (size_t)(bb * NUM_HEADS + hh) * SEQ + sloc + sl;
        invL[idx] = 1.f / (Lp[loff] + Lp[65536 + loff]);
    }
    __syncthreads();

    f4v acc[4][2];
#pragma unroll
    for (int i = 0; i < 4; ++i)
#pragma unroll
        for (int j = 0; j < 2; ++j) acc[i][j] = (f4v){0.f, 0.f, 0.f, 0.f};

    for (int k0 = 0; k0 < D_MODEL; k0 += 64) {
        const int h = k0 >> 6;
#pragma unroll
        for (int i = 0; i < 2; ++i) {
            const int cid = i * 256 + w * 64 + lane;
            const int row = cid >> 3, pp = cid & 7, g = pp ^ (row & 7);
            gld_lds16(&Wob[(size_t)(n0 + row) * D_MODEL + k0 + g * 8],
                      &Bs[(i * 256 + w * 64) * 8]);
        }
        const size_t obase = ((size_t)(bb * NUM_HEADS + h) * SEQ + sloc) * D_HEAD;
#pragma unroll
        for (int i = 0; i < 4; ++i) {
            const int cid = i * 256 + t;
            const int row = cid >> 3, pp = cid & 7, g = pp ^ (row & 7);
            const size_t off = obase + (size_t)row * D_HEAD + g * 8;
            int4 a0 = *(const int4*)&Op0[off];
            int4 a1 = *(const int4*)&Op1[off];
            const float inv = invL[h * 128 + row];
            const unsigned* u0 = (const unsigned*)&a0;
            const unsigned* u1 = (const unsigned*)&a1;
            int4 o;
#pragma unroll
            for (int d = 0; d < 4; ++d) {
                float lo = (__uint_as_float(u0[d] << 16) +
                            __uint_as_float(u1[d] << 16)) * inv;
                float hi = (__uint_as_float(u0[d] & 0xffff0000u) +
                            __uint_as_float(u1[d] & 0xffff0000u)) * inv;
                ((unsigned*)&o)[d] = (__float_as_uint(lo) >> 16) |
                                     (__float_as_uint(hi) & 0xffff0000u);
            }
            *(int4*)&As[cid * 8] = o;
        }
        __syncthreads();

#pragma unroll
        for (int c = 0; c < 2; ++c) {
            s8v af[4], bf[2];
            const int pos = ((c * 4 + quad) ^ (l15 & 7)) * 8;
#pragma unroll
            for (int mi = 0; mi < 4; ++mi)
                af[mi] = *(const s8v*)&As[(wm * 64 + mi * 16 + l15) * 64 + pos];
#pragma unroll
            for (int ni = 0; ni < 2; ++ni)
                bf[ni] = *(const s8v*)&Bs[(wn * 32 + ni * 16 + l15) * 64 + pos];
#pragma unroll
            for (int mi = 0; mi < 4; ++mi)
#pragma unroll
                for (int ni = 0; ni < 2; ++ni)
                    acc[mi][ni] = __builtin_amdgcn_mfma_f32_16x16x32_bf16(
                        af[mi], bf[ni], acc[mi][ni], 0, 0, 0);
        }
        __syncthreads();
    }

#pragma unroll
    for (int ni = 0; ni < 2; ++ni) {
        const int col = n0 + wn * 32 + ni * 16 + l15;
        const float bv = bo[col];
#pragma unroll
        for (int mi = 0; mi < 4; ++mi)
#pragma unroll
            for (int r = 0; r < 4; ++r) {
                const int row = m0 + wm * 64 + mi * 16 + quad * 4 + r;
                out[(size_t)row * D_MODEL + col] = acc[mi][ni][r] + bv;
            }
    }
}

// ---------------------------------------------------------------------------
extern "C" void kernel_launch(void* const* d_in, const int* in_sizes, int n_in,
                              void* d_out, int out_size, void* d_ws, size_t ws_size,
                              hipStream_t stream)
{
    const float* x  = (const float*)d_in[0];
    const float* Wq = (const float*)d_in[1];
    const float* bq = (const float*)d_in[2];
    const float* Wk = (const float*)d_in[3];
    const float* bk = (const float*)d_in[4];
    const float* Wv = (const float*)d_in[5];
    const float* bv = (const float*)d_in[6];
    const float* Wo = (const float*)d_in[7];
    const float* bo = (const float*)d_in[8];
    float* out = (float*)d_out;

    short* wsp = (short*)d_ws;
    const size_t MAT = (size_t)NROWS * D_MODEL;   // 4 Mi elements
    short* Qb    = wsp;                           // [ 0, 8) MB  bf16 Q (exp2 scale)
    short* Kbg   = Qb + MAT;                      // [ 8,16) MB  bf16 K
    short* Vtb   = Kbg + MAT;                     // [16,24) MB  bf16 V^T
    short* Xb    = Vtb + 2 * MAT;                 // [32,40) MB  bf16 x (dead after QKV)
    short* Wqkvb = Xb + MAT;                      // [40,46) MB
    short* Wob   = Wqkvb + 3 * D_MODEL * D_MODEL; // [46,48) MB
    short* Op0   = Xb;                            // seg0 partial O aliases Xb
    short* Op1   = Wob + D_MODEL * D_MODEL;       // [48,56) MB
    float* Lp    = (float*)(Op1 + MAT);           // [56,56.5) MB: 2 x 64K floats

    cvt_fused<<<8192, 256, 0, stream>>>(x, Wq, Wk, Wv, Wo, Xb, Wqkvb, Wob);

    gemm_qkv<<<768, 256, 0, stream>>>(Xb, Wqkvb, bq, bk, bv, Qb, Kbg, Vtb);

    attn_mfma<<<1024, 256, 0, stream>>>(Qb, Kbg, Vtb, Op0, Op1, Lp);

    gemm_oproj<<<dim3(D_MODEL / 64, NROWS / 128), 256, 0, stream>>>(
        Op0, Op1, Lp, Wob, bo, out);
}

// Round 10
// 197.692 us; speedup vs baseline: 13.3283x; 1.0436x over previous
//
#include <hip/hip_runtime.h>
#include <math.h>

#define D_MODEL 1024
#define NUM_HEADS 16
#define D_HEAD 64
#define SEQ 2048
#define BATCH 2
#define NROWS (BATCH * SEQ) /* 4096 */

typedef short s8v __attribute__((ext_vector_type(8)));   // 8 bf16 (4 VGPRs)
typedef float f4v __attribute__((ext_vector_type(4)));   // MFMA C/D

__device__ __forceinline__ short to_bf(float f) {
    union { float f; unsigned u; } x; x.f = f;
    unsigned r = x.u + 0x7fffu + ((x.u >> 16) & 1u);   // RNE
    return (short)(r >> 16);
}

__device__ __forceinline__ unsigned pack_bf2(float a, float b) {
    return (unsigned)(unsigned short)to_bf(a) | ((unsigned)(unsigned short)to_bf(b) << 16);
}

// raw v_exp_f32 (exp2): 1 instruction vs OCML exp2f's denormal-fixup path
__device__ __forceinline__ float fast_exp2(float x) {
    return __builtin_amdgcn_exp2f(x);
}

// async global->LDS, 16 B/lane; LDS dest is wave-uniform base + lane*16
__device__ __forceinline__ void gld_lds16(const short* g, short* l) {
    __builtin_amdgcn_global_load_lds(
        (const __attribute__((address_space(1))) unsigned*)g,
        (__attribute__((address_space(3))) unsigned*)l, 16, 0, 0);
}

// Q pre-scale: 1/sqrt(Dh) * log2(e)  -> S leaves MFMA in exp2 domain
#define QSCALE 0.180336880f

// ---------------------------------------------------------------------------
// fp32 -> bf16 convert. Wq segment pre-scaled by QSCALE.
// ---------------------------------------------------------------------------
__global__ __launch_bounds__(256) void cvt_fused(
    const float* __restrict__ x,  const float* __restrict__ Wq,
    const float* __restrict__ Wk, const float* __restrict__ Wv,
    const float* __restrict__ Wo,
    short* __restrict__ Xb, short* __restrict__ Wqkvb, short* __restrict__ Wob)
{
    const int NX = NROWS * D_MODEL / 4;
    const int NW = D_MODEL * D_MODEL / 4;
    int j = blockIdx.x * 256 + threadIdx.x;
    const float* src; short* dst; float sc = 1.f;
    if (j < NX)                 { src = x;  dst = Xb; }
    else if ((j -= NX) < NW)    { src = Wq; dst = Wqkvb; sc = QSCALE; }
    else if ((j -= NW) < NW)    { src = Wk; dst = Wqkvb + NW * 4; }
    else if ((j -= NW) < NW)    { src = Wv; dst = Wqkvb + NW * 8; }
    else                        { j -= NW; src = Wo; dst = Wob; }
    float4 v = ((const float4*)src)[j];
    short4 s = { to_bf(v.x * sc), to_bf(v.y * sc), to_bf(v.z * sc), to_bf(v.w * sc) };
    ((short4*)dst)[j] = s;
}

// ---------------------------------------------------------------------------
// QKV bf16 MFMA GEMM (unchanged from R9): 128x128, BK=64, XOR-swizzled LDS,
// XCD-locality grid (768 blocks).  Q/K: transposed accumulate -> direct 8-B
// stores into [B,H,S,Dh].  V: normal -> direct stores into V^T [B,H,Dh,S].
// ---------------------------------------------------------------------------
__global__ __launch_bounds__(256) void gemm_qkv(
    const short* __restrict__ Xb, const short* __restrict__ Wb,
    const float* __restrict__ B0, const float* __restrict__ B1, const float* __restrict__ B2,
    short* __restrict__ Q0, short* __restrict__ K1, short* __restrict__ V2)
{
    __shared__ __align__(16) short As[128 * 64];   // 16 KB
    __shared__ __align__(16) short Bs[128 * 64];   // 16 KB

    const int t    = threadIdx.x;
    const int w    = t >> 6;
    const int lane = t & 63;
    const int quad = lane >> 4;
    const int l15  = lane & 15;
    const int wm   = w & 1, wn = w >> 1;

    const int bx    = blockIdx.x;
    const int xcd   = bx & 7;
    const int g_    = bx >> 3;            // 0..95
    const int n_loc = g_ % 12;
    const int m_loc = g_ / 12;            // 0..7
    const int n0 = ((xcd >> 2) * 12 + n_loc) * 128;
    const int m0 = ((xcd & 3) * 8 + m_loc) * 128;

    const bool swapT = (n0 < 2048);       // Q/K -> transposed accumulate

    f4v acc[4][4];
#pragma unroll
    for (int i = 0; i < 4; ++i)
#pragma unroll
        for (int j = 0; j < 4; ++j) acc[i][j] = (f4v){0.f, 0.f, 0.f, 0.f};

    for (int k0 = 0; k0 < D_MODEL; k0 += 64) {
#pragma unroll
        for (int i = 0; i < 4; ++i) {
            const int cid = i * 256 + t;
            const int row = cid >> 3, kc = cid & 7, g = kc ^ (row & 7);
            gld_lds16(&Xb[(size_t)(m0 + row) * D_MODEL + k0 + g * 8],
                      &As[(i * 256 + w * 64) * 8]);
            gld_lds16(&Wb[(size_t)(n0 + row) * D_MODEL + k0 + g * 8],
                      &Bs[(i * 256 + w * 64) * 8]);
        }
        __syncthreads();

#pragma unroll
        for (int c = 0; c < 2; ++c) {
            s8v af[4], bf[4];
            const int pos = ((c * 4 + quad) ^ (l15 & 7)) * 8;
#pragma unroll
            for (int mi = 0; mi < 4; ++mi)
                af[mi] = *(const s8v*)&As[(wm * 64 + mi * 16 + l15) * 64 + pos];
#pragma unroll
            for (int ni = 0; ni < 4; ++ni)
                bf[ni] = *(const s8v*)&Bs[(wn * 64 + ni * 16 + l15) * 64 + pos];
            if (swapT) {
#pragma unroll
                for (int mi = 0; mi < 4; ++mi)
#pragma unroll
                    for (int ni = 0; ni < 4; ++ni)
                        acc[mi][ni] = __builtin_amdgcn_mfma_f32_16x16x32_bf16(
                            bf[ni], af[mi], acc[mi][ni], 0, 0, 0);
            } else {
#pragma unroll
                for (int mi = 0; mi < 4; ++mi)
#pragma unroll
                    for (int ni = 0; ni < 4; ++ni)
                        acc[mi][ni] = __builtin_amdgcn_mfma_f32_16x16x32_bf16(
                            af[mi], bf[ni], acc[mi][ni], 0, 0, 0);
            }
        }
        __syncthreads();
    }

    if (swapT) {
        const int sel = n0 >> 10;                   // 0 or 1
        const float* bias = sel == 0 ? B0 : B1;
        short* out        = sel == 0 ? Q0 : K1;
        const float bsc   = sel == 0 ? QSCALE : 1.f;
        const int nb = n0 & 1023;
#pragma unroll
        for (int ni = 0; ni < 4; ++ni) {
            const int colb = nb + wn * 64 + ni * 16 + quad * 4;   // 4-aligned
            float4 bv = *(const float4*)&bias[colb];
            const int h = colb >> 6, dh = colb & 63;
#pragma unroll
            for (int mi = 0; mi < 4; ++mi) {
                const int row = m0 + wm * 64 + mi * 16 + l15;
                const int bb = row >> 11, sl = row & (SEQ - 1);
                int2 pk;
                pk.x = (int)pack_bf2(acc[mi][ni][0] + bv.x * bsc,
                                     acc[mi][ni][1] + bv.y * bsc);
                pk.y = (int)pack_bf2(acc[mi][ni][2] + bv.z * bsc,
                                     acc[mi][ni][3] + bv.w * bsc);
                *(int2*)&out[(((size_t)(bb * NUM_HEADS + h) * SEQ) + sl) * D_HEAD + dh] = pk;
            }
        }
    } else {
        const int nb = n0 & 1023;
#pragma unroll
        for (int ni = 0; ni < 4; ++ni) {
            const int col = nb + wn * 64 + ni * 16 + l15;
            const int h = col >> 6, dh = col & 63;
            const float bv = B2[col];
#pragma unroll
            for (int mi = 0; mi < 4; ++mi) {
                const int row = m0 + wm * 64 + mi * 16 + quad * 4;
                const int bb = row >> 11, sl = row & (SEQ - 1);
                int2 pk;
                pk.x = (int)pack_bf2(acc[mi][ni][0] + bv, acc[mi][ni][1] + bv);
                pk.y = (int)pack_bf2(acc[mi][ni][2] + bv, acc[mi][ni][3] + bv);
                *(int2*)&V2[((size_t)(bb * NUM_HEADS + h) * D_HEAD + dh) * SEQ + sl] = pk;
            }
        }
    }
}

// ---------------------------------------------------------------------------
// MFMA flash attention v6: identical to v5 except exp2f -> raw v_exp_f32
// (__builtin_amdgcn_exp2f).  Key-split flash-decoding, 1024 blocks,
// fixed-shift additive partials -> Op0/Op1 (bf16) + Lp (fp32).
// ---------------------------------------------------------------------------
__global__ __launch_bounds__(256) void attn_mfma(
    const short* __restrict__ Qg, const short* __restrict__ Kg,
    const short* __restrict__ Vg,
    short* __restrict__ Op0, short* __restrict__ Op1, float* __restrict__ Lp)
{
    __shared__ __align__(16) short Kb[128 * 64];     // 16 KB  [key][d]
    __shared__ __align__(16) short Vs[64 * 128];     // 16 KB  [d][key]
    __shared__ __align__(16) short Ps[4][32 * 72];   // 18 KB  per-wave [q][key64]

    const int t    = threadIdx.x;
    const int w    = t >> 6;
    const int lane = t & 63;
    const int quad = lane >> 4;
    const int l15  = lane & 15;

    const int bidx = blockIdx.x;
    const int seg  = bidx >> 9;               // key parity
    const int p    = bidx & 255;
    const int bh   = p >> 3;
    const int pair = p & 7;
    const int qt   = ((bidx >> 8) & 1) ? 15 - pair : pair;

    const short* qbase = Qg + (size_t)bh * SEQ * D_HEAD;
    const short* kbase = Kg + (size_t)bh * SEQ * D_HEAD;
    const short* vbase = Vg + (size_t)bh * D_HEAD * SEQ;
    const int q0 = qt * 128;
    const int qw = w * 32;

    s8v aq[2][2];
#pragma unroll
    for (int ns = 0; ns < 2; ++ns)
#pragma unroll
        for (int c = 0; c < 2; ++c)
            aq[ns][c] = *(const s8v*)&qbase[(size_t)(q0 + qw + ns * 16 + l15) * D_HEAD
                                            + c * 32 + quad * 8];

    f4v Oacc[2][4];
#pragma unroll
    for (int ms = 0; ms < 2; ++ms)
#pragma unroll
        for (int nt = 0; nt < 4; ++nt) Oacc[ms][nt] = (f4v){0.f, 0.f, 0.f, 0.f};
    float lsum[2] = {0.f, 0.f};

    for (int j = seg; j <= qt; j += 2) {
        __syncthreads();
        {
            const int k0 = j * 128;
#pragma unroll
            for (int i = 0; i < 4; ++i) {
                const int cid = i * 256 + w * 64 + lane;
                {
                    const int row = cid >> 3, pp = cid & 7, g = pp ^ (row & 7);
                    gld_lds16(&kbase[(size_t)(k0 + row) * D_HEAD + g * 8],
                              &Kb[(i * 256 + w * 64) * 8]);
                }
                {
                    const int row = cid >> 4, pp = cid & 15;
                    const int g = (pp & 8) | ((pp & 7) ^ (row & 7));
                    gld_lds16(&vbase[(size_t)row * SEQ + k0 + g * 8],
                              &Vs[(i * 256 + w * 64) * 8]);
                }
            }
        }
        __syncthreads();

        const bool diag = (j == qt);

#pragma unroll
        for (int half = 0; half < 2; ++half) {
#pragma unroll
            for (int mt = 0; mt < 4; ++mt) {
                const int krow = half * 64 + mt * 16 + l15;
                s8v ka0 = *(const s8v*)&Kb[(krow * 8 + (quad ^ (l15 & 7))) * 8];
                s8v ka1 = *(const s8v*)&Kb[(krow * 8 + ((4 + quad) ^ (l15 & 7))) * 8];
#pragma unroll
                for (int ns = 0; ns < 2; ++ns) {
                    f4v st = (f4v){0.f, 0.f, 0.f, 0.f};
                    st = __builtin_amdgcn_mfma_f32_16x16x32_bf16(ka0, aq[ns][0], st, 0, 0, 0);
                    st = __builtin_amdgcn_mfma_f32_16x16x32_bf16(ka1, aq[ns][1], st, 0, 0, 0);
                    if (diag) {
#pragma unroll
                        for (int r = 0; r < 4; ++r)
                            if (half * 64 + mt * 16 + quad * 4 + r > qw + ns * 16 + l15)
                                st[r] = -INFINITY;
                    }
                    float e0 = fast_exp2(st[0]), e1 = fast_exp2(st[1]);
                    float e2 = fast_exp2(st[2]), e3 = fast_exp2(st[3]);
                    lsum[ns] += (e0 + e1) + (e2 + e3);
                    int2 pk;
                    pk.x = (int)((__float_as_uint(e0) >> 16) | (__float_as_uint(e1) & 0xffff0000u));
                    pk.y = (int)((__float_as_uint(e2) >> 16) | (__float_as_uint(e3) & 0xffff0000u));
                    *(int2*)&Ps[w][(ns * 16 + l15) * 72 + mt * 16 + quad * 4] = pk;
                }
            }
#pragma unroll
            for (int c2 = 0; c2 < 2; ++c2) {
                s8v ap0 = *(const s8v*)&Ps[w][l15 * 72 + c2 * 32 + quad * 8];
                s8v ap1 = *(const s8v*)&Ps[w][(16 + l15) * 72 + c2 * 32 + quad * 8];
                const int g = (half * 2 + c2) * 4 + quad;
                const int pos = (g & 8) | ((g & 7) ^ (l15 & 7));
                s8v bv[4];
#pragma unroll
                for (int nt = 0; nt < 4; ++nt)
                    bv[nt] = *(const s8v*)&Vs[((nt * 16 + l15) * 16 + pos) * 8];
#pragma unroll
                for (int nt = 0; nt < 4; ++nt) {
                    Oacc[0][nt] = __builtin_amdgcn_mfma_f32_16x16x32_bf16(
                        ap0, bv[nt], Oacc[0][nt], 0, 0, 0);
                    Oacc[1][nt] = __builtin_amdgcn_mfma_f32_16x16x32_bf16(
                        ap1, bv[nt], Oacc[1][nt], 0, 0, 0);
                }
            }
        }
    }

#pragma unroll
    for (int ns = 0; ns < 2; ++ns) {
        lsum[ns] += __shfl_xor(lsum[ns], 16, 64);
        lsum[ns] += __shfl_xor(lsum[ns], 32, 64);
    }
    float* L = Lp + ((size_t)seg << 16) + (size_t)bh * SEQ;
    if (quad == 0) {
        L[q0 + qw + l15]      = lsum[0];
        L[q0 + qw + 16 + l15] = lsum[1];
    }
    short* Op = (seg ? Op1 : Op0) + (size_t)bh * SEQ * D_HEAD;
#pragma unroll
    for (int ms = 0; ms < 2; ++ms)
#pragma unroll
        for (int r = 0; r < 4; ++r) {
            const int nloc = q0 + qw + ms * 16 + quad * 4 + r;
            short* dst = Op + (size_t)nloc * D_HEAD + l15;
#pragma unroll
            for (int nt = 0; nt < 4; ++nt)
                dst[nt * 16] = to_bf(Oacc[ms][nt][r]);
        }
}

// ---------------------------------------------------------------------------
// O-projection with FUSED combine (unchanged from R8): 128M x 64N, grid 512.
// ---------------------------------------------------------------------------
__global__ __launch_bounds__(256) void gemm_oproj(
    const short* __restrict__ Op0, const short* __restrict__ Op1,
    const float* __restrict__ Lp, const short* __restrict__ Wob,
    const float* __restrict__ bo, float* __restrict__ out)
{
    __shared__ __align__(16) short As[128 * 64];   // 16 KB
    __shared__ __align__(16) short Bs[64 * 64];    //  8 KB
    __shared__ float invL[NUM_HEADS * 128];        //  8 KB: inv[h][row]

    const int t    = threadIdx.x;
    const int w    = t >> 6;
    const int lane = t & 63;
    const int quad = lane >> 4;
    const int l15  = lane & 15;
    const int wm   = w & 1, wn = w >> 1;

    const int n0 = blockIdx.x * 64;
    const int m0 = blockIdx.y * 128;
    const int bb = m0 >> 11, sloc = m0 & (SEQ - 1);

#pragma unroll
    for (int ii = 0; ii < 8; ++ii) {
        const int idx = t * 8 + ii;
        const int hh = idx >> 7, sl = idx & 127;
        const size_t loff = (size_t)(bb * NUM_HEADS + hh) * SEQ + sloc + sl;
        invL[idx] = 1.f / (Lp[loff] + Lp[65536 + loff]);
    }
    __syncthreads();

    f4v acc[4][2];
#pragma unroll
    for (int i = 0; i < 4; ++i)
#pragma unroll
        for (int j = 0; j < 2; ++j) acc[i][j] = (f4v){0.f, 0.f, 0.f, 0.f};

    for (int k0 = 0; k0 < D_MODEL; k0 += 64) {
        const int h = k0 >> 6;
#pragma unroll
        for (int i = 0; i < 2; ++i) {
            const int cid = i * 256 + w * 64 + lane;
            const int row = cid >> 3, pp = cid & 7, g = pp ^ (row & 7);
            gld_lds16(&Wob[(size_t)(n0 + row) * D_MODEL + k0 + g * 8],
                      &Bs[(i * 256 + w * 64) * 8]);
        }
        const size_t obase = ((size_t)(bb * NUM_HEADS + h) * SEQ + sloc) * D_HEAD;
#pragma unroll
        for (int i = 0; i < 4; ++i) {
            const int cid = i * 256 + t;
            const int row = cid >> 3, pp = cid & 7, g = pp ^ (row & 7);
            const size_t off = obase + (size_t)row * D_HEAD + g * 8;
            int4 a0 = *(const int4*)&Op0[off];
            int4 a1 = *(const int4*)&Op1[off];
            const float inv = invL[h * 128 + row];
            const unsigned* u0 = (const unsigned*)&a0;
            const unsigned* u1 = (const unsigned*)&a1;
            int4 o;
#pragma unroll
            for (int d = 0; d < 4; ++d) {
                float lo = (__uint_as_float(u0[d] << 16) +
                            __uint_as_float(u1[d] << 16)) * inv;
                float hi = (__uint_as_float(u0[d] & 0xffff0000u) +
                            __uint_as_float(u1[d] & 0xffff0000u)) * inv;
                ((unsigned*)&o)[d] = (__float_as_uint(lo) >> 16) |
                                     (__float_as_uint(hi) & 0xffff0000u);
            }
            *(int4*)&As[cid * 8] = o;
        }
        __syncthreads();

#pragma unroll
        for (int c = 0; c < 2; ++c) {
            s8v af[4], bf[2];
            const int pos = ((c * 4 + quad) ^ (l15 & 7)) * 8;
#pragma unroll
            for (int mi = 0; mi < 4; ++mi)
                af[mi] = *(const s8v*)&As[(wm * 64 + mi * 16 + l15) * 64 + pos];
#pragma unroll
            for (int ni = 0; ni < 2; ++ni)
                bf[ni] = *(const s8v*)&Bs[(wn * 32 + ni * 16 + l15) * 64 + pos];
#pragma unroll
            for (int mi = 0; mi < 4; ++mi)
#pragma unroll
                for (int ni = 0; ni < 2; ++ni)
                    acc[mi][ni] = __builtin_amdgcn_mfma_f32_16x16x32_bf16(
                        af[mi], bf[ni], acc[mi][ni], 0, 0, 0);
        }
        __syncthreads();
    }

#pragma unroll
    for (int ni = 0; ni < 2; ++ni) {
        const int col = n0 + wn * 32 + ni * 16 + l15;
        const float bv = bo[col];
#pragma unroll
        for (int mi = 0; mi < 4; ++mi)
#pragma unroll
            for (int r = 0; r < 4; ++r) {
                const int row = m0 + wm * 64 + mi * 16 + quad * 4 + r;
                out[(size_t)row * D_MODEL + col] = acc[mi][ni][r] + bv;
            }
    }
}

// ---------------------------------------------------------------------------
extern "C" void kernel_launch(void* const* d_in, const int* in_sizes, int n_in,
                              void* d_out, int out_size, void* d_ws, size_t ws_size,
                              hipStream_t stream)
{
    const float* x  = (const float*)d_in[0];
    const float* Wq = (const float*)d_in[1];
    const float* bq = (const float*)d_in[2];
    const float* Wk = (const float*)d_in[3];
    const float* bk = (const float*)d_in[4];
    const float* Wv = (const float*)d_in[5];
    const float* bv = (const float*)d_in[6];
    const float* Wo = (const float*)d_in[7];
    const float* bo = (const float*)d_in[8];
    float* out = (float*)d_out;

    short* wsp = (short*)d_ws;
    const size_t MAT = (size_t)NROWS * D_MODEL;   // 4 Mi elements
    short* Qb    = wsp;                           // [ 0, 8) MB  bf16 Q (exp2 scale)
    short* Kbg   = Qb + MAT;                      // [ 8,16) MB  bf16 K
    short* Vtb   = Kbg + MAT;                     // [16,24) MB  bf16 V^T
    short* Xb    = Vtb + 2 * MAT;                 // [32,40) MB  bf16 x (dead after QKV)
    short* Wqkvb = Xb + MAT;                      // [40,46) MB
    short* Wob   = Wqkvb + 3 * D_MODEL * D_MODEL; // [46,48) MB
    short* Op0   = Xb;                            // seg0 partial O aliases Xb
    short* Op1   = Wob + D_MODEL * D_MODEL;       // [48,56) MB
    float* Lp    = (float*)(Op1 + MAT);           // [56,56.5) MB: 2 x 64K floats

    cvt_fused<<<8192, 256, 0, stream>>>(x, Wq, Wk, Wv, Wo, Xb, Wqkvb, Wob);

    gemm_qkv<<<768, 256, 0, stream>>>(Xb, Wqkvb, bq, bk, bv, Qb, Kbg, Vtb);

    attn_mfma<<<1024, 256, 0, stream>>>(Qb, Kbg, Vtb, Op0, Op1, Lp);

    gemm_oproj<<<dim3(D_MODEL / 64, NROWS / 128), 256, 0, stream>>>(
        Op0, Op1, Lp, Wob, bo, out);
}